// Round 1
// baseline (10911.301 us; speedup 1.0000x reference)
//
#include <hip/hip_runtime.h>
#include <hip/hip_bf16.h>

#define D 512
#define NH 8
#define HD 64
#define BATCH 2048
#define SEQ 32
#define MIND 16
#define KHS 66   // padded stride (bf16 elems) for per-head K/V tiles: 132B row stride -> conflict-free

typedef __hip_bfloat16 bf16;

__device__ __forceinline__ float b2f(bf16 x) { return __bfloat162float(x); }
__device__ __forceinline__ bf16  f2b(float x) { return __float2bfloat16(x); }

__device__ __forceinline__ float wave_sum(float v) {
#pragma unroll
    for (int off = 32; off >= 1; off >>= 1) v += __shfl_xor(v, off, 64);
    return v;
}

// Q0[16][512] = I[0] @ Wq0 + bq0   (batch-independent: I is broadcast over B)
__global__ __launch_bounds__(256) void q0_kernel(
    const float* __restrict__ I, const float* __restrict__ Wq,
    const float* __restrict__ bq, float* __restrict__ Q0)
{
    const int q = blockIdx.x;
    const int c = threadIdx.x;
    float a0 = 0.f, a1 = 0.f;
    for (int k = 0; k < D; ++k) {
        const float iv = I[q * D + k];
        a0 = fmaf(iv, Wq[k * D + c], a0);
        a1 = fmaf(iv, Wq[k * D + c + 256], a1);
    }
    Q0[q * D + c]       = a0 + bq[c];
    Q0[q * D + c + 256] = a1 + bq[c + 256];
}

// Fully-fused MAB: one workgroup per batch element, 256 threads (4 waves).
// LDS plan (dynamic):
//   [0,4K)      stage: fp32 staging chunk for Q-projection input
//   [4K,6K)     sS: fp32 scores [SQ][SK]
//   [6400,..)   sKh: bf16 [SK][KHS] per-head K
//   [10752,..)  sVh: bf16 [SK][KHS] per-head V
//   [16K,..)    sQ: bf16 [SQ][512]  (Q -> O -> ln0(O))
//   [16K+SQ*1K) sKin: bf16 [SK][512]; reused as sT [SQ][512] after attention
template <int SQ, int SK, bool PREQ>
__global__ __launch_bounds__(256) void mab_fused(
    const float* __restrict__ Qin, const float* __restrict__ Q0,
    const float* __restrict__ Kin,
    const float* __restrict__ Wq, const float* __restrict__ bq,
    const float* __restrict__ Wk, const float* __restrict__ bk,
    const float* __restrict__ Wv, const float* __restrict__ bv,
    const float* __restrict__ Wo, const float* __restrict__ bo,
    const float* __restrict__ g0, const float* __restrict__ b0,
    const float* __restrict__ g1, const float* __restrict__ b1,
    float* __restrict__ out)
{
    extern __shared__ char smem[];
    float* stage = (float*)(smem);
    float* sS    = (float*)(smem + 4096);
    bf16*  sKh   = (bf16*)(smem + 6400);
    bf16*  sVh   = (bf16*)(smem + 10752);
    bf16*  sQ    = (bf16*)(smem + 16384);
    bf16*  sKin  = (bf16*)(smem + 16384 + SQ * 1024);
    bf16*  sT    = sKin;   // region size = max(SK,SQ)*1024 bytes

    const int tid  = threadIdx.x;
    const int lane = tid & 63;
    const int wv   = tid >> 6;
    const int b    = blockIdx.x;

    // ---- load Kin[b] -> sKin (bf16) ----
    const float* kin = Kin + (size_t)b * SK * D;
    for (int idx = tid; idx < SK * D; idx += 256) sKin[idx] = f2b(kin[idx]);

    // ---- Q: precomputed (mab0) or projected from Qin[b] (mab1) ----
    if (PREQ) {
        for (int idx = tid; idx < SQ * D; idx += 256) sQ[idx] = f2b(Q0[idx]);
        __syncthreads();
    } else {
        const float* qin = Qin + (size_t)b * SQ * D;
        float acc[2 * SQ];
#pragma unroll
        for (int i = 0; i < 2 * SQ; ++i) acc[i] = 0.f;
        const int c0 = 2 * tid;   // this thread owns output columns c0, c0+1
        for (int k0 = 0; k0 < D; k0 += 32) {
            __syncthreads();
            for (int idx = tid; idx < SQ * 32; idx += 256) {
                const int i = idx >> 5, kc = idx & 31;
                stage[idx] = qin[i * D + k0 + kc];
            }
            __syncthreads();
#pragma unroll 2
            for (int kc = 0; kc < 32; ++kc) {
                const float w0 = Wq[(size_t)(k0 + kc) * D + c0];
                const float w1 = Wq[(size_t)(k0 + kc) * D + c0 + 1];
#pragma unroll
                for (int i = 0; i < SQ; ++i) {
                    const float a = stage[i * 32 + kc];   // LDS broadcast
                    acc[2 * i]     = fmaf(a, w0, acc[2 * i]);
                    acc[2 * i + 1] = fmaf(a, w1, acc[2 * i + 1]);
                }
            }
        }
        const float bb0 = bq[c0], bb1 = bq[c0 + 1];
#pragma unroll
        for (int i = 0; i < SQ; ++i) {
            sQ[i * D + c0]     = f2b(acc[2 * i] + bb0);
            sQ[i * D + c0 + 1] = f2b(acc[2 * i + 1] + bb1);
        }
        __syncthreads();
    }

    const float scale = 0.044194173824159216f;   // 1/sqrt(512)

    // ---- per-head attention: Kh/Vh projection, scores, softmax, O = Q + A*V ----
#pragma unroll 1
    for (int h = 0; h < NH; ++h) {
        constexpr int RPT = SK / 4;   // rows per thread (4 waves cover SK rows)
        {
            float ka[RPT], va[RPT];
#pragma unroll
            for (int r = 0; r < RPT; ++r) { ka[r] = 0.f; va[r] = 0.f; }
            const float* wkh = Wk + h * HD + lane;
            const float* wvh = Wv + h * HD + lane;
#pragma unroll 4
            for (int k = 0; k < D; ++k) {
                const float wkv = wkh[(size_t)k * D];   // coalesced, L2-hit
                const float wvv = wvh[(size_t)k * D];
#pragma unroll
                for (int r = 0; r < RPT; ++r) {
                    const float a = b2f(sKin[(wv * RPT + r) * D + k]);  // broadcast
                    ka[r] = fmaf(a, wkv, ka[r]);
                    va[r] = fmaf(a, wvv, va[r]);
                }
            }
            const float bkv = bk[h * HD + lane];
            const float bvv = bv[h * HD + lane];
#pragma unroll
            for (int r = 0; r < RPT; ++r) {
                sKh[(wv * RPT + r) * KHS + lane] = f2b(ka[r] + bkv);
                sVh[(wv * RPT + r) * KHS + lane] = f2b(va[r] + bvv);
            }
        }
        __syncthreads();

        // scores[q][k] = (Qh[q] . Kh[k]) * scale
        for (int o = tid; o < SQ * SK; o += 256) {
            const int q = o / SK, k = o % SK;
            float s = 0.f;
#pragma unroll
            for (int d0 = 0; d0 < HD; ++d0)
                s = fmaf(b2f(sQ[q * D + h * HD + d0]), b2f(sKh[k * KHS + d0]), s);
            sS[o] = s * scale;
        }
        __syncthreads();

        if (tid < SQ) {   // softmax over k, one thread per q-row (tiny)
            float* row = sS + tid * SK;
            float m = row[0];
#pragma unroll
            for (int k = 1; k < SK; ++k) m = fmaxf(m, row[k]);
            float sum = 0.f;
#pragma unroll
            for (int k = 0; k < SK; ++k) { const float e = __expf(row[k] - m); row[k] = e; sum += e; }
            const float inv = 1.f / sum;
#pragma unroll
            for (int k = 0; k < SK; ++k) row[k] *= inv;
        }
        __syncthreads();

        // O_h = Q_h + A * V_h (in place in sQ head columns)
        constexpr int QPT = SQ / 4;
#pragma unroll
        for (int r = 0; r < QPT; ++r) {
            const int q = wv * QPT + r;
            float o = 0.f;
#pragma unroll
            for (int k = 0; k < SK; ++k)
                o = fmaf(sS[q * SK + k], b2f(sVh[k * KHS + lane]), o);
            const int off = q * D + h * HD + lane;
            sQ[off] = f2b(b2f(sQ[off]) + o);
        }
        __syncthreads();
    }

    // ---- ln0 in place on sQ: one wave per row ----
    for (int i = wv; i < SQ; i += 4) {
        bf16* row = sQ + i * D;
        float v[8];
#pragma unroll
        for (int j = 0; j < 8; ++j) v[j] = b2f(row[lane + 64 * j]);
        float s = 0.f;
#pragma unroll
        for (int j = 0; j < 8; ++j) s += v[j];
        s = wave_sum(s);
        const float mu = s * (1.f / 512.f);
        float q2 = 0.f;
#pragma unroll
        for (int j = 0; j < 8; ++j) { const float t = v[j] - mu; q2 = fmaf(t, t, q2); }
        q2 = wave_sum(q2);
        const float inv = rsqrtf(q2 * (1.f / 512.f) + 1e-5f);
#pragma unroll
        for (int j = 0; j < 8; ++j) {
            const int d0 = lane + 64 * j;
            row[d0] = f2b((v[j] - mu) * inv * g0[d0] + b0[d0]);
        }
    }
    __syncthreads();

    // ---- FFN: sT = O @ Wo + bo (sKin region is dead -> reuse as sT) ----
    {
        float acc[2 * SQ];
#pragma unroll
        for (int i = 0; i < 2 * SQ; ++i) acc[i] = 0.f;
        const int c0 = 2 * tid;
#pragma unroll 2
        for (int k = 0; k < D; ++k) {
            const float w0 = Wo[(size_t)k * D + c0];
            const float w1 = Wo[(size_t)k * D + c0 + 1];
#pragma unroll
            for (int i = 0; i < SQ; ++i) {
                const float a = b2f(sQ[i * D + k]);
                acc[2 * i]     = fmaf(a, w0, acc[2 * i]);
                acc[2 * i + 1] = fmaf(a, w1, acc[2 * i + 1]);
            }
        }
        const float bb0 = bo[c0], bb1 = bo[c0 + 1];
#pragma unroll
        for (int i = 0; i < SQ; ++i) {
            sT[i * D + c0]     = f2b(acc[2 * i] + bb0);
            sT[i * D + c0 + 1] = f2b(acc[2 * i + 1] + bb1);
        }
    }
    __syncthreads();

    // ---- U = O + relu(T); ln1; write out (fp32) ----
    float* ob = out + (size_t)b * SQ * D;
    for (int i = wv; i < SQ; i += 4) {
        float v[8];
#pragma unroll
        for (int j = 0; j < 8; ++j) {
            const int d0 = lane + 64 * j;
            v[j] = b2f(sQ[i * D + d0]) + fmaxf(b2f(sT[i * D + d0]), 0.f);
        }
        float s = 0.f;
#pragma unroll
        for (int j = 0; j < 8; ++j) s += v[j];
        s = wave_sum(s);
        const float mu = s * (1.f / 512.f);
        float q2 = 0.f;
#pragma unroll
        for (int j = 0; j < 8; ++j) { const float t = v[j] - mu; q2 = fmaf(t, t, q2); }
        q2 = wave_sum(q2);
        const float inv = rsqrtf(q2 * (1.f / 512.f) + 1e-5f);
#pragma unroll
        for (int j = 0; j < 8; ++j) {
            const int d0 = lane + 64 * j;
            ob[i * D + d0] = (v[j] - mu) * inv * g1[d0] + b1[d0];
        }
    }
}

__global__ __launch_bounds__(512) void mean_kernel(const float* __restrict__ X,
                                                   float* __restrict__ out)
{
    const int b  = blockIdx.x;
    const int d0 = threadIdx.x;
    const float* xb = X + (size_t)b * SEQ * D;
    float s = 0.f;
#pragma unroll
    for (int i = 0; i < SEQ; ++i) s += xb[i * D + d0];
    out[(size_t)b * D + d0] = s * (1.0f / SEQ);
}

extern "C" void kernel_launch(void* const* d_in, const int* in_sizes, int n_in,
                              void* d_out, int out_size, void* d_ws, size_t ws_size,
                              hipStream_t stream) {
    (void)in_sizes; (void)n_in; (void)out_size; (void)ws_size;

    const float* x     = (const float*)d_in[0];
    const float* I     = (const float*)d_in[1];
    const float* W0    = (const float*)d_in[2];
    const float* bqkv0 = (const float*)d_in[3];
    const float* Wo0   = (const float*)d_in[4];
    const float* bo0   = (const float*)d_in[5];
    const float* g00   = (const float*)d_in[6];
    const float* b00   = (const float*)d_in[7];
    const float* g01   = (const float*)d_in[8];
    const float* b01   = (const float*)d_in[9];
    const float* W1    = (const float*)d_in[10];
    const float* bqkv1 = (const float*)d_in[11];
    const float* Wo1   = (const float*)d_in[12];
    const float* bo1   = (const float*)d_in[13];
    const float* g10   = (const float*)d_in[14];
    const float* b10   = (const float*)d_in[15];
    const float* g11   = (const float*)d_in[16];
    const float* b11   = (const float*)d_in[17];

    const float* Wq0 = W0;             const float* Wk0 = W0 + D * D;  const float* Wv0 = W0 + 2 * D * D;
    const float* bq0 = bqkv0;          const float* bk0 = bqkv0 + D;   const float* bv0 = bqkv0 + 2 * D;
    const float* Wq1 = W1;             const float* Wk1 = W1 + D * D;  const float* Wv1 = W1 + 2 * D * D;
    const float* bq1 = bqkv1;          const float* bk1 = bqkv1 + D;   const float* bv1 = bqkv1 + 2 * D;

    char* ws = (char*)d_ws;
    float* Q0 = (float*)ws;                                        // 16*512*4   = 32 KB
    float* Hm = (float*)(ws + 32768);                              // B*16*512*4 = 64 MB
    float* Xb = (float*)(ws + 32768 + (size_t)BATCH * MIND * D * 4); // B*32*512*4 = 128 MB

    constexpr size_t lds0 = 16384 + (size_t)MIND * 1024 + (size_t)SEQ * 1024;  // 64 KB
    constexpr size_t lds1 = 16384 + (size_t)SEQ * 1024 + (size_t)SEQ * 1024;   // 80 KB

    // Q for mab0 is batch-independent (I broadcast) and shared by both ISABs.
    q0_kernel<<<MIND, 256, 0, stream>>>(I, Wq0, bq0, Q0);

    // ISAB 1:  Hm = mab0(I, x);  h1 = mab1(x, Hm)
    mab_fused<MIND, SEQ, true><<<BATCH, 256, lds0, stream>>>(
        nullptr, Q0, x, nullptr, nullptr, Wk0, bk0, Wv0, bv0,
        Wo0, bo0, g00, b00, g01, b01, Hm);
    mab_fused<SEQ, MIND, false><<<BATCH, 256, lds1, stream>>>(
        x, nullptr, Hm, Wq1, bq1, Wk1, bk1, Wv1, bv1,
        Wo1, bo1, g10, b10, g11, b11, Xb);

    // ISAB 2:  Hm = mab0(I, h1); h2 = mab1(h1, Hm)  (in-place per-block safe)
    mab_fused<MIND, SEQ, true><<<BATCH, 256, lds0, stream>>>(
        nullptr, Q0, Xb, nullptr, nullptr, Wk0, bk0, Wv0, bv0,
        Wo0, bo0, g00, b00, g01, b01, Hm);
    mab_fused<SEQ, MIND, false><<<BATCH, 256, lds1, stream>>>(
        Xb, nullptr, Hm, Wq1, bq1, Wk1, bk1, Wv1, bv1,
        Wo1, bo1, g10, b10, g11, b11, Xb);

    mean_kernel<<<BATCH, 512, 0, stream>>>(Xb, (float*)d_out);
}

// Round 3
// 2374.909 us; speedup vs baseline: 4.5944x; 4.5944x over previous
//
#include <hip/hip_runtime.h>
#include <hip/hip_bf16.h>

#define D 512
#define NH 8
#define BATCH 2048
#define SEQ 32
#define MIND 16

typedef __hip_bfloat16 bf16;
typedef __attribute__((ext_vector_type(8))) short s8v;   // 8 bf16 = 4 VGPR (MFMA A/B frag)
typedef __attribute__((ext_vector_type(4))) short s4v;
typedef __attribute__((ext_vector_type(4))) float f4v;   // MFMA C/D frag

// byte-offset swizzle for [row][512] bf16 LDS tiles: XOR bits 4-6 with row&7
// -> 16-lane column reads spread over 8 distinct 16B slots (conflict-free b128)
#define SWZ(row, kb) (((row) << 10) + ((kb) ^ (((row) & 7) << 4)))

__device__ __forceinline__ ushort f2bu(float f) {
    bf16 h = __float2bfloat16(f); ushort u; __builtin_memcpy(&u, &h, 2); return u;
}
__device__ __forceinline__ float bu2f(ushort u) {
    unsigned x = ((unsigned)u) << 16; float f; __builtin_memcpy(&f, &x, 4); return f;
}

__device__ __forceinline__ float wave_sum(float v) {
#pragma unroll
    for (int off = 32; off >= 1; off >>= 1) v += __shfl_xor(v, off, 64);
    return v;
}

// ---------------- weight pre-transpose: W[k][n] fp32 -> Wt[n][k] bf16 ----------------
__global__ __launch_bounds__(256) void wtrans(const float* __restrict__ W,
                                              ushort* __restrict__ Wt) {
    __shared__ float t[32][33];
    const int k0 = blockIdx.x * 32, n0 = blockIdx.y * 32;
    const int lx = threadIdx.x & 31, ly = threadIdx.x >> 5;
    for (int i = ly; i < 32; i += 8) t[i][lx] = W[(size_t)(k0 + i) * D + n0 + lx];
    __syncthreads();
    for (int i = ly; i < 32; i += 8)
        Wt[(size_t)(n0 + i) * D + k0 + lx] = f2bu(t[lx][i]);
}

// ---------------- Q0[16][512] = I @ Wq0 + bq0 (batch-independent) ----------------
__global__ __launch_bounds__(256) void q0_kernel(
    const float* __restrict__ I, const float* __restrict__ Wq,
    const float* __restrict__ bq, float* __restrict__ Q0)
{
    const int q = blockIdx.x;
    const int c = threadIdx.x;
    float a0 = 0.f, a1 = 0.f;
    for (int k = 0; k < D; ++k) {
        const float iv = I[q * D + k];
        a0 = fmaf(iv, Wq[(size_t)k * D + c], a0);
        a1 = fmaf(iv, Wq[(size_t)k * D + c + 256], a1);
    }
    Q0[q * D + c]       = a0 + bq[c];
    Q0[q * D + c + 256] = a1 + bq[c + 256];
}

// ---------------- MFMA GEMM helpers ----------------
// C[MR][512] = A(sA, swizzled bf16 LDS) @ Wt(global bf16 [n][k]) + bias -> sC (swizzled bf16)
// wave wv owns cols [wv*64, wv*64+64). Internal barrier allows sC to alias sA.
template <int MR>
__device__ __forceinline__ void gemm_ws(const char* sA, const ushort* __restrict__ Wt,
                                        const float* __restrict__ bias, char* sC,
                                        int lane, int wv) {
    constexpr int RT = MR / 16;
    f4v acc[RT][4];
#pragma unroll
    for (int i = 0; i < RT; ++i)
#pragma unroll
        for (int j = 0; j < 4; ++j) acc[i][j] = (f4v){0.f, 0.f, 0.f, 0.f};
    const int m = lane & 15, g = lane >> 4;
    const int swm = (m & 7) << 4;
#pragma unroll 4
    for (int k0 = 0; k0 < 512; k0 += 32) {
        const int kb = 2 * (k0 + 8 * g);
        s8v a[RT];
#pragma unroll
        for (int rt = 0; rt < RT; ++rt)
            a[rt] = *(const s8v*)(sA + ((rt * 16 + m) << 10) + (kb ^ swm));
#pragma unroll
        for (int ct = 0; ct < 4; ++ct) {
            const s8v bfr = *(const s8v*)(Wt + ((size_t)(wv * 64 + ct * 16 + m) << 9) + k0 + 8 * g);
#pragma unroll
            for (int rt = 0; rt < RT; ++rt)
                acc[rt][ct] = __builtin_amdgcn_mfma_f32_16x16x32_bf16(a[rt], bfr, acc[rt][ct], 0, 0, 0);
        }
    }
    __syncthreads();   // all waves done reading sA before (possibly aliased) writes
#pragma unroll
    for (int ct = 0; ct < 4; ++ct) {
        const int col = wv * 64 + ct * 16 + m;
        const float bb = bias[col];
#pragma unroll
        for (int rt = 0; rt < RT; ++rt)
#pragma unroll
            for (int r = 0; r < 4; ++r) {
                const int row = rt * 16 + g * 4 + r;
                *(ushort*)(sC + SWZ(row, 2 * col)) = f2bu(acc[rt][ct][r] + bb);
            }
    }
}

// dual-output variant: K and V share the A fragments (one pass over sA)
template <int MR>
__device__ __forceinline__ void gemm_dual_ws(const char* sA,
                                             const ushort* __restrict__ WtK, const float* __restrict__ bK,
                                             const ushort* __restrict__ WtV, const float* __restrict__ bV,
                                             char* sCK, char* sCV, int lane, int wv) {
    constexpr int RT = MR / 16;
    f4v accK[RT][4], accV[RT][4];
#pragma unroll
    for (int i = 0; i < RT; ++i)
#pragma unroll
        for (int j = 0; j < 4; ++j) {
            accK[i][j] = (f4v){0.f, 0.f, 0.f, 0.f};
            accV[i][j] = (f4v){0.f, 0.f, 0.f, 0.f};
        }
    const int m = lane & 15, g = lane >> 4;
    const int swm = (m & 7) << 4;
#pragma unroll 4
    for (int k0 = 0; k0 < 512; k0 += 32) {
        const int kb = 2 * (k0 + 8 * g);
        s8v a[RT];
#pragma unroll
        for (int rt = 0; rt < RT; ++rt)
            a[rt] = *(const s8v*)(sA + ((rt * 16 + m) << 10) + (kb ^ swm));
#pragma unroll
        for (int ct = 0; ct < 4; ++ct) {
            const size_t nro = ((size_t)(wv * 64 + ct * 16 + m) << 9) + k0 + 8 * g;
            const s8v bk_ = *(const s8v*)(WtK + nro);
            const s8v bv_ = *(const s8v*)(WtV + nro);
#pragma unroll
            for (int rt = 0; rt < RT; ++rt) {
                accK[rt][ct] = __builtin_amdgcn_mfma_f32_16x16x32_bf16(a[rt], bk_, accK[rt][ct], 0, 0, 0);
                accV[rt][ct] = __builtin_amdgcn_mfma_f32_16x16x32_bf16(a[rt], bv_, accV[rt][ct], 0, 0, 0);
            }
        }
    }
    __syncthreads();   // sCV aliases sA (V overwrites the staged input)
#pragma unroll
    for (int ct = 0; ct < 4; ++ct) {
        const int col = wv * 64 + ct * 16 + m;
        const float bbk = bK[col], bbv = bV[col];
#pragma unroll
        for (int rt = 0; rt < RT; ++rt)
#pragma unroll
            for (int r = 0; r < 4; ++r) {
                const int row = rt * 16 + g * 4 + r;
                *(ushort*)(sCK + SWZ(row, 2 * col)) = f2bu(accK[rt][ct][r] + bbk);
                *(ushort*)(sCV + SWZ(row, 2 * col)) = f2bu(accV[rt][ct][r] + bbv);
            }
    }
}

// ---------------- fused MAB: 1 block / batch element, 512 threads = 8 waves ----------------
template <int SQ, int SK, bool PREQ, bool KIN_BF16, bool OUT_BF16, bool MEANPOOL>
__global__ __launch_bounds__(512) void mab2(
    const float* __restrict__ Qin, const float* __restrict__ Q0,
    const void* __restrict__ Kin,
    const ushort* __restrict__ WtQ, const float* __restrict__ bq,
    const ushort* __restrict__ WtK, const float* __restrict__ bk,
    const ushort* __restrict__ WtV, const float* __restrict__ bv,
    const ushort* __restrict__ WtO, const float* __restrict__ bo,
    const float* __restrict__ g0, const float* __restrict__ b0,
    const float* __restrict__ g1, const float* __restrict__ b1,
    void* __restrict__ out)
{
    constexpr int SKP = SK + 1;
    __shared__ __align__(16) char smem[2 * SK * 1024 + SQ * 1024 + 8 * SQ * SKP * 4];
    char* sK    = smem;                       // K proj [SK][512] swizzled
    char* sV    = smem + SK * 1024;           // staged Kin, then V proj [SK][512]
    char* sQm   = smem + 2 * SK * 1024;       // Q -> O -> ln0(O) [SQ][512]
    float* sSal = (float*)(smem + 2 * SK * 1024 + SQ * 1024);  // per-wave scores
    char* sT    = smem;                       // FFN out [SQ][512] (sK+sV regions dead)

    const int tid = threadIdx.x, lane = tid & 63, wv = tid >> 6;
    const int b = blockIdx.x;

    // ---- stage Kin[b] -> sV (bf16, swizzled) ----
    if constexpr (KIN_BF16) {
        const ushort* kin = (const ushort*)Kin + (size_t)b * SK * D;
        for (int c = tid; c < SK * (D / 4); c += 512) {
            const int row = c >> 7, k4 = (c & 127) << 2;
            *(s4v*)(sV + SWZ(row, k4 * 2)) = *(const s4v*)(kin + (row << 9) + k4);
        }
    } else {
        const float* kin = (const float*)Kin + (size_t)b * SK * D;
        for (int c = tid; c < SK * (D / 4); c += 512) {
            const int row = c >> 7, k4 = (c & 127) << 2;
            const float4 v = *(const float4*)(kin + (row << 9) + k4);
            s4v o = {(short)f2bu(v.x), (short)f2bu(v.y), (short)f2bu(v.z), (short)f2bu(v.w)};
            *(s4v*)(sV + SWZ(row, k4 * 2)) = o;
        }
    }
    // ---- stage Q source -> sQm ----
    {
        const float* qsrc = PREQ ? Q0 : (Qin + (size_t)b * SQ * D);
        for (int c = tid; c < SQ * (D / 4); c += 512) {
            const int row = c >> 7, k4 = (c & 127) << 2;
            const float4 v = *(const float4*)(qsrc + (row << 9) + k4);
            s4v o = {(short)f2bu(v.x), (short)f2bu(v.y), (short)f2bu(v.z), (short)f2bu(v.w)};
            *(s4v*)(sQm + SWZ(row, k4 * 2)) = o;
        }
    }
    __syncthreads();

    if constexpr (!PREQ) gemm_ws<SQ>(sQm, WtQ, bq, sQm, lane, wv);   // Q proj in place
    gemm_dual_ws<SK>(sV, WtK, bk, WtV, bv, sK, sV, lane, wv);        // K,V proj (V over input)
    __syncthreads();

    // ---- attention: wave wv <-> head wv (each wave owns its 64 head-cols) ----
    {
        const int h64 = wv * 64;
        float* myS = sSal + wv * SQ * SKP;
        const float scale = 0.044194173824159216f;   // 1/sqrt(512)
        // scores
#pragma unroll
        for (int o = 0; o < SQ * SK / 64; ++o) {
            const int idx = o * 64 + lane;
            const int q = idx / SK, k = idx % SK;
            float s = 0.f;
#pragma unroll
            for (int dd = 0; dd < 64; dd += 8) {
                const s8v aq = *(const s8v*)(sQm + SWZ(q, 2 * (h64 + dd)));
                const s8v ak = *(const s8v*)(sK + SWZ(k, 2 * (h64 + dd)));
#pragma unroll
                for (int e = 0; e < 8; ++e)
                    s = fmaf(bu2f((ushort)aq[e]), bu2f((ushort)ak[e]), s);
            }
            myS[q * SKP + k] = s * scale;
        }
        __syncthreads();
        // softmax (lane q owns row q; SK <= 32 serial)
        if (lane < SQ) {
            float* row = myS + lane * SKP;
            float mx = row[0];
#pragma unroll
            for (int k = 1; k < SK; ++k) mx = fmaxf(mx, row[k]);
            float sum = 0.f;
#pragma unroll
            for (int k = 0; k < SK; ++k) { const float e = __expf(row[k] - mx); row[k] = e; sum += e; }
            const float inv = 1.f / sum;
#pragma unroll
            for (int k = 0; k < SK; ++k) row[k] *= inv;
        }
        __syncthreads();
        // PV + residual: lane owns d0 = lane within the head
        float acc[SQ];
#pragma unroll
        for (int q = 0; q < SQ; ++q) acc[q] = 0.f;
#pragma unroll 4
        for (int k = 0; k < SK; ++k) {
            const float v = bu2f(*(const ushort*)(sV + SWZ(k, 2 * (h64 + lane))));
#pragma unroll
            for (int q = 0; q < SQ; ++q) acc[q] = fmaf(myS[q * SKP + k], v, acc[q]);
        }
#pragma unroll
        for (int q = 0; q < SQ; ++q) {
            ushort* p = (ushort*)(sQm + SWZ(q, 2 * (h64 + lane)));
            *p = f2bu(bu2f(*p) + acc[q]);
        }
    }
    __syncthreads();

    // ---- ln0 in place on sQm ----
    for (int i = wv; i < SQ; i += 8) {
        float v[8];
#pragma unroll
        for (int j = 0; j < 8; ++j) v[j] = bu2f(*(const ushort*)(sQm + SWZ(i, 2 * (lane + 64 * j))));
        float s = 0.f;
#pragma unroll
        for (int j = 0; j < 8; ++j) s += v[j];
        s = wave_sum(s);
        const float mu = s * (1.f / 512.f);
        float q2 = 0.f;
#pragma unroll
        for (int j = 0; j < 8; ++j) { const float t = v[j] - mu; q2 = fmaf(t, t, q2); }
        q2 = wave_sum(q2);
        const float inv = rsqrtf(q2 * (1.f / 512.f) + 1e-5f);
#pragma unroll
        for (int j = 0; j < 8; ++j) {
            const int d0 = lane + 64 * j;
            *(ushort*)(sQm + SWZ(i, 2 * d0)) = f2bu((v[j] - mu) * inv * g0[d0] + b0[d0]);
        }
    }
    __syncthreads();

    // ---- FFN: sT = ln0(O) @ Wo + bo ----
    gemm_ws<SQ>(sQm, WtO, bo, sT, lane, wv);
    __syncthreads();

    // ---- U = O + relu(T); ln1; output ----
    for (int i = wv; i < SQ; i += 8) {
        float v[8];
#pragma unroll
        for (int j = 0; j < 8; ++j) {
            const int d0 = lane + 64 * j;
            v[j] = bu2f(*(const ushort*)(sQm + SWZ(i, 2 * d0))) +
                   fmaxf(bu2f(*(const ushort*)(sT + SWZ(i, 2 * d0))), 0.f);
        }
        float s = 0.f;
#pragma unroll
        for (int j = 0; j < 8; ++j) s += v[j];
        s = wave_sum(s);
        const float mu = s * (1.f / 512.f);
        float q2 = 0.f;
#pragma unroll
        for (int j = 0; j < 8; ++j) { const float t = v[j] - mu; q2 = fmaf(t, t, q2); }
        q2 = wave_sum(q2);
        const float inv = rsqrtf(q2 * (1.f / 512.f) + 1e-5f);
        if constexpr (MEANPOOL) {
#pragma unroll
            for (int j = 0; j < 8; ++j) {
                const int d0 = lane + 64 * j;
                *(ushort*)(sQm + SWZ(i, 2 * d0)) = f2bu((v[j] - mu) * inv * g1[d0] + b1[d0]);
            }
        } else if constexpr (OUT_BF16) {
            ushort* ob = (ushort*)out + (size_t)b * SQ * D;
#pragma unroll
            for (int j = 0; j < 8; ++j) {
                const int d0 = lane + 64 * j;
                ob[i * D + d0] = f2bu((v[j] - mu) * inv * g1[d0] + b1[d0]);
            }
        } else {
            float* ob = (float*)out + (size_t)b * SQ * D;
#pragma unroll
            for (int j = 0; j < 8; ++j) {
                const int d0 = lane + 64 * j;
                ob[i * D + d0] = (v[j] - mu) * inv * g1[d0] + b1[d0];
            }
        }
    }
    if constexpr (MEANPOOL) {
        __syncthreads();
        float s = 0.f;
#pragma unroll 8
        for (int i = 0; i < SQ; ++i) s += bu2f(*(const ushort*)(sQm + SWZ(i, 2 * tid)));
        ((float*)out)[(size_t)b * D + tid] = s * (1.f / SQ);
    }
}

extern "C" void kernel_launch(void* const* d_in, const int* in_sizes, int n_in,
                              void* d_out, int out_size, void* d_ws, size_t ws_size,
                              hipStream_t stream) {
    (void)in_sizes; (void)n_in; (void)out_size; (void)ws_size;

    const float* x     = (const float*)d_in[0];
    const float* I     = (const float*)d_in[1];
    const float* W0    = (const float*)d_in[2];
    const float* bqkv0 = (const float*)d_in[3];
    const float* Wo0   = (const float*)d_in[4];
    const float* bo0   = (const float*)d_in[5];
    const float* g00   = (const float*)d_in[6];
    const float* b00   = (const float*)d_in[7];
    const float* g01   = (const float*)d_in[8];
    const float* b01   = (const float*)d_in[9];
    const float* W1    = (const float*)d_in[10];
    const float* bqkv1 = (const float*)d_in[11];
    const float* Wo1   = (const float*)d_in[12];
    const float* bo1   = (const float*)d_in[13];
    const float* g10   = (const float*)d_in[14];
    const float* b10   = (const float*)d_in[15];
    const float* g11   = (const float*)d_in[16];
    const float* b11   = (const float*)d_in[17];

    const float* Wq0 = W0;     const float* Wk0 = W0 + D * D;  const float* Wv0 = W0 + 2 * D * D;
    const float* bq0 = bqkv0;  const float* bk0 = bqkv0 + D;   const float* bv0 = bqkv0 + 2 * D;
    const float* Wq1 = W1;     const float* Wk1 = W1 + D * D;  const float* Wv1 = W1 + 2 * D * D;
    const float* bq1 = bqkv1;  const float* bk1 = bqkv1 + D;   const float* bv1 = bqkv1 + 2 * D;

    char* ws = (char*)d_ws;
    float*  Q0  = (float*)ws;                                   // 32 KB
    ushort* Wt  = (ushort*)(ws + 32768);                        // 7 x 512 KB bf16
    ushort* Hm  = (ushort*)(ws + 32768 + 7 * 524288);           // B*16*512 bf16 = 32 MB
    float*  Xb  = (float*)(ws + 32768 + 7 * 524288 + (size_t)BATCH * MIND * D * 2);  // 128 MB

    ushort* WtK0 = Wt + 0 * 262144;
    ushort* WtV0 = Wt + 1 * 262144;
    ushort* WtO0 = Wt + 2 * 262144;
    ushort* WtQ1 = Wt + 3 * 262144;
    ushort* WtK1 = Wt + 4 * 262144;
    ushort* WtV1 = Wt + 5 * 262144;
    ushort* WtO1 = Wt + 6 * 262144;

    dim3 tg(16, 16);
    wtrans<<<tg, 256, 0, stream>>>(Wk0, WtK0);
    wtrans<<<tg, 256, 0, stream>>>(Wv0, WtV0);
    wtrans<<<tg, 256, 0, stream>>>(Wo0, WtO0);
    wtrans<<<tg, 256, 0, stream>>>(Wq1, WtQ1);
    wtrans<<<tg, 256, 0, stream>>>(Wk1, WtK1);
    wtrans<<<tg, 256, 0, stream>>>(Wv1, WtV1);
    wtrans<<<tg, 256, 0, stream>>>(Wo1, WtO1);
    q0_kernel<<<MIND, 256, 0, stream>>>(I, Wq0, bq0, Q0);

    // ISAB 1: Hm = mab0(I, x); h1(Xb) = mab1(x, Hm)
    mab2<MIND, SEQ, true, false, true, false><<<BATCH, 512, 0, stream>>>(
        nullptr, Q0, x, nullptr, nullptr, WtK0, bk0, WtV0, bv0, WtO0, bo0,
        g00, b00, g01, b01, Hm);
    mab2<SEQ, MIND, false, true, false, false><<<BATCH, 512, 0, stream>>>(
        x, nullptr, Hm, WtQ1, bq1, WtK1, bk1, WtV1, bv1, WtO1, bo1,
        g10, b10, g11, b11, Xb);

    // ISAB 2: Hm = mab0(I, h1); out = meanpool(mab1(h1, Hm))
    mab2<MIND, SEQ, true, false, true, false><<<BATCH, 512, 0, stream>>>(
        nullptr, Q0, Xb, nullptr, nullptr, WtK0, bk0, WtV0, bv0, WtO0, bo0,
        g00, b00, g01, b01, Hm);
    mab2<SEQ, MIND, false, true, false, true><<<BATCH, 512, 0, stream>>>(
        Xb, nullptr, Hm, WtQ1, bq1, WtK1, bk1, WtV1, bv1, WtO1, bo1,
        g10, b10, g11, b11, d_out);
}

// Round 4
// 2366.402 us; speedup vs baseline: 4.6109x; 1.0036x over previous
//
#include <hip/hip_runtime.h>
#include <hip/hip_bf16.h>

#define D 512
#define NH 8
#define BATCH 2048
#define SEQ 32
#define MIND 16

typedef __hip_bfloat16 bf16;
typedef __attribute__((ext_vector_type(8))) short s8v;   // 8 bf16 = 4 VGPR (MFMA A/B frag)
typedef __attribute__((ext_vector_type(4))) short s4v;
typedef __attribute__((ext_vector_type(4))) float f4v;   // MFMA C/D frag

// byte-offset swizzle for [row][512] bf16 LDS tiles: XOR bits 4-6 with row&7
// -> 16-lane column reads spread over 8 distinct 16B slots (conflict-free b128)
#define SWZ(row, kb) (((row) << 10) + ((kb) ^ (((row) & 7) << 4)))

__device__ __forceinline__ ushort f2bu(float f) {
    bf16 h = __float2bfloat16(f); ushort u; __builtin_memcpy(&u, &h, 2); return u;
}
__device__ __forceinline__ float bu2f(ushort u) {
    unsigned x = ((unsigned)u) << 16; float f; __builtin_memcpy(&f, &x, 4); return f;
}

__device__ __forceinline__ float wave_sum(float v) {
#pragma unroll
    for (int off = 32; off >= 1; off >>= 1) v += __shfl_xor(v, off, 64);
    return v;
}

// ---------------- weight pre-transpose: W[k][n] fp32 -> Wt[n][k] bf16 ----------------
__global__ __launch_bounds__(256) void wtrans(const float* __restrict__ W,
                                              ushort* __restrict__ Wt) {
    __shared__ float t[32][33];
    const int k0 = blockIdx.x * 32, n0 = blockIdx.y * 32;
    const int lx = threadIdx.x & 31, ly = threadIdx.x >> 5;
    for (int i = ly; i < 32; i += 8) t[i][lx] = W[(size_t)(k0 + i) * D + n0 + lx];
    __syncthreads();
    for (int i = ly; i < 32; i += 8)
        Wt[(size_t)(n0 + i) * D + k0 + lx] = f2bu(t[lx][i]);
}

// ---------------- Q0[16][512] = I @ Wq0 + bq0 (batch-independent) ----------------
__global__ __launch_bounds__(256) void q0_kernel(
    const float* __restrict__ I, const float* __restrict__ Wq,
    const float* __restrict__ bq, float* __restrict__ Q0)
{
    const int q = blockIdx.x;
    const int c = threadIdx.x;
    float a0 = 0.f, a1 = 0.f;
    for (int k = 0; k < D; ++k) {
        const float iv = I[q * D + k];
        a0 = fmaf(iv, Wq[(size_t)k * D + c], a0);
        a1 = fmaf(iv, Wq[(size_t)k * D + c + 256], a1);
    }
    Q0[q * D + c]       = a0 + bq[c];
    Q0[q * D + c + 256] = a1 + bq[c + 256];
}

// ---------------- MFMA GEMM helpers (register-pipelined B prefetch) ----------------
// C[MR][512] = A(sA, swizzled bf16 LDS) @ Wt(global bf16 [n][k]) + bias -> sC (swizzled bf16)
// wave wv owns cols [wv*64, wv*64+64). Internal barrier allows sC to alias sA.
// Depth-2 register prefetch of B: loads issued ~2 iterations ahead of MFMA use.
template <int MR>
__device__ __forceinline__ void gemm_ws(const char* sA, const ushort* __restrict__ Wt,
                                        const float* __restrict__ bias, char* sC,
                                        int lane, int wv) {
    constexpr int RT = MR / 16;
    f4v acc[RT][4];
#pragma unroll
    for (int i = 0; i < RT; ++i)
#pragma unroll
        for (int j = 0; j < 4; ++j) acc[i][j] = (f4v){0.f, 0.f, 0.f, 0.f};
    const int m = lane & 15, g = lane >> 4;
    const int swm = (m & 7) << 4;
    const ushort* Bp = Wt + ((size_t)(wv * 64 + m) << 9) + 8 * g;
    s8v b0[4], b1[4];
#pragma unroll
    for (int ct = 0; ct < 4; ++ct) b0[ct] = *(const s8v*)(Bp + ct * 8192);
#pragma unroll
    for (int ct = 0; ct < 4; ++ct) b1[ct] = *(const s8v*)(Bp + ct * 8192 + 32);
#pragma unroll
    for (int k0 = 0; k0 < 512; k0 += 32) {
        s8v bn[4];
        if (k0 < 448) {
#pragma unroll
            for (int ct = 0; ct < 4; ++ct) bn[ct] = *(const s8v*)(Bp + ct * 8192 + k0 + 64);
        }
        const int kb = 2 * (k0 + 8 * g);
        s8v a[RT];
#pragma unroll
        for (int rt = 0; rt < RT; ++rt)
            a[rt] = *(const s8v*)(sA + ((rt * 16 + m) << 10) + (kb ^ swm));
#pragma unroll
        for (int ct = 0; ct < 4; ++ct)
#pragma unroll
            for (int rt = 0; rt < RT; ++rt)
                acc[rt][ct] = __builtin_amdgcn_mfma_f32_16x16x32_bf16(a[rt], b0[ct], acc[rt][ct], 0, 0, 0);
#pragma unroll
        for (int ct = 0; ct < 4; ++ct) { b0[ct] = b1[ct]; b1[ct] = bn[ct]; }
    }
    __syncthreads();   // all waves done reading sA before (possibly aliased) writes
#pragma unroll
    for (int ct = 0; ct < 4; ++ct) {
        const int col = wv * 64 + ct * 16 + m;
        const float bb = bias[col];
#pragma unroll
        for (int rt = 0; rt < RT; ++rt)
#pragma unroll
            for (int r = 0; r < 4; ++r) {
                const int row = rt * 16 + g * 4 + r;
                *(ushort*)(sC + SWZ(row, 2 * col)) = f2bu(acc[rt][ct][r] + bb);
            }
    }
}

// dual-output variant: K and V share the A fragments (one pass over sA), depth-2 prefetch
template <int MR>
__device__ __forceinline__ void gemm_dual_ws(const char* sA,
                                             const ushort* __restrict__ WtK, const float* __restrict__ bK,
                                             const ushort* __restrict__ WtV, const float* __restrict__ bV,
                                             char* sCK, char* sCV, int lane, int wv) {
    constexpr int RT = MR / 16;
    f4v accK[RT][4], accV[RT][4];
#pragma unroll
    for (int i = 0; i < RT; ++i)
#pragma unroll
        for (int j = 0; j < 4; ++j) {
            accK[i][j] = (f4v){0.f, 0.f, 0.f, 0.f};
            accV[i][j] = (f4v){0.f, 0.f, 0.f, 0.f};
        }
    const int m = lane & 15, g = lane >> 4;
    const int swm = (m & 7) << 4;
    const size_t ro = ((size_t)(wv * 64 + m) << 9) + 8 * g;
    const ushort* BK = WtK + ro;
    const ushort* BV = WtV + ro;
    s8v bk0[4], bv0[4], bk1[4], bv1[4];
#pragma unroll
    for (int ct = 0; ct < 4; ++ct) {
        bk0[ct] = *(const s8v*)(BK + ct * 8192);
        bv0[ct] = *(const s8v*)(BV + ct * 8192);
    }
#pragma unroll
    for (int ct = 0; ct < 4; ++ct) {
        bk1[ct] = *(const s8v*)(BK + ct * 8192 + 32);
        bv1[ct] = *(const s8v*)(BV + ct * 8192 + 32);
    }
#pragma unroll
    for (int k0 = 0; k0 < 512; k0 += 32) {
        s8v bkn[4], bvn[4];
        if (k0 < 448) {
#pragma unroll
            for (int ct = 0; ct < 4; ++ct) {
                bkn[ct] = *(const s8v*)(BK + ct * 8192 + k0 + 64);
                bvn[ct] = *(const s8v*)(BV + ct * 8192 + k0 + 64);
            }
        }
        const int kb = 2 * (k0 + 8 * g);
        s8v a[RT];
#pragma unroll
        for (int rt = 0; rt < RT; ++rt)
            a[rt] = *(const s8v*)(sA + ((rt * 16 + m) << 10) + (kb ^ swm));
#pragma unroll
        for (int ct = 0; ct < 4; ++ct)
#pragma unroll
            for (int rt = 0; rt < RT; ++rt) {
                accK[rt][ct] = __builtin_amdgcn_mfma_f32_16x16x32_bf16(a[rt], bk0[ct], accK[rt][ct], 0, 0, 0);
                accV[rt][ct] = __builtin_amdgcn_mfma_f32_16x16x32_bf16(a[rt], bv0[ct], accV[rt][ct], 0, 0, 0);
            }
#pragma unroll
        for (int ct = 0; ct < 4; ++ct) {
            bk0[ct] = bk1[ct]; bk1[ct] = bkn[ct];
            bv0[ct] = bv1[ct]; bv1[ct] = bvn[ct];
        }
    }
    __syncthreads();   // sCV aliases sA (V overwrites the staged input)
#pragma unroll
    for (int ct = 0; ct < 4; ++ct) {
        const int col = wv * 64 + ct * 16 + m;
        const float bbk = bK[col], bbv = bV[col];
#pragma unroll
        for (int rt = 0; rt < RT; ++rt)
#pragma unroll
            for (int r = 0; r < 4; ++r) {
                const int row = rt * 16 + g * 4 + r;
                *(ushort*)(sCK + SWZ(row, 2 * col)) = f2bu(accK[rt][ct][r] + bbk);
                *(ushort*)(sCV + SWZ(row, 2 * col)) = f2bu(accV[rt][ct][r] + bbv);
            }
    }
}

// triple: Q proj (A = sQ, in place) + K,V proj (A = sKV, V in place) in ONE k-loop.
// Depth-1 prefetch on all three B streams (VGPR budget).
template <int MQ, int MKV>
__device__ __forceinline__ void gemm_triple_ws(
    char* sQ, const ushort* __restrict__ WtQ, const float* __restrict__ bq,
    char* sKV, const ushort* __restrict__ WtK, const float* __restrict__ bk,
    const ushort* __restrict__ WtV, const float* __restrict__ bv,
    char* sK, int lane, int wv)
{
    constexpr int RQ = MQ / 16, RK = MKV / 16;
    f4v aQ[RQ][4], aK[RK][4], aV[RK][4];
#pragma unroll
    for (int i = 0; i < RQ; ++i)
#pragma unroll
        for (int j = 0; j < 4; ++j) aQ[i][j] = (f4v){0.f, 0.f, 0.f, 0.f};
#pragma unroll
    for (int i = 0; i < RK; ++i)
#pragma unroll
        for (int j = 0; j < 4; ++j) {
            aK[i][j] = (f4v){0.f, 0.f, 0.f, 0.f};
            aV[i][j] = (f4v){0.f, 0.f, 0.f, 0.f};
        }
    const int m = lane & 15, g = lane >> 4;
    const int swm = (m & 7) << 4;
    const size_t ro = ((size_t)(wv * 64 + m) << 9) + 8 * g;
    const ushort *BQ = WtQ + ro, *BK = WtK + ro, *BV = WtV + ro;
    s8v bq0[4], bk0[4], bv0[4];
#pragma unroll
    for (int ct = 0; ct < 4; ++ct) {
        bq0[ct] = *(const s8v*)(BQ + ct * 8192);
        bk0[ct] = *(const s8v*)(BK + ct * 8192);
        bv0[ct] = *(const s8v*)(BV + ct * 8192);
    }
#pragma unroll
    for (int k0 = 0; k0 < 512; k0 += 32) {
        s8v bq1[4], bk1[4], bv1[4];
        if (k0 < 480) {
#pragma unroll
            for (int ct = 0; ct < 4; ++ct) {
                bq1[ct] = *(const s8v*)(BQ + ct * 8192 + k0 + 32);
                bk1[ct] = *(const s8v*)(BK + ct * 8192 + k0 + 32);
                bv1[ct] = *(const s8v*)(BV + ct * 8192 + k0 + 32);
            }
        }
        const int kb = 2 * (k0 + 8 * g);
        s8v a_q[RQ], a_kv[RK];
#pragma unroll
        for (int rt = 0; rt < RQ; ++rt)
            a_q[rt] = *(const s8v*)(sQ + ((rt * 16 + m) << 10) + (kb ^ swm));
#pragma unroll
        for (int rt = 0; rt < RK; ++rt)
            a_kv[rt] = *(const s8v*)(sKV + ((rt * 16 + m) << 10) + (kb ^ swm));
#pragma unroll
        for (int ct = 0; ct < 4; ++ct) {
#pragma unroll
            for (int rt = 0; rt < RQ; ++rt)
                aQ[rt][ct] = __builtin_amdgcn_mfma_f32_16x16x32_bf16(a_q[rt], bq0[ct], aQ[rt][ct], 0, 0, 0);
#pragma unroll
            for (int rt = 0; rt < RK; ++rt) {
                aK[rt][ct] = __builtin_amdgcn_mfma_f32_16x16x32_bf16(a_kv[rt], bk0[ct], aK[rt][ct], 0, 0, 0);
                aV[rt][ct] = __builtin_amdgcn_mfma_f32_16x16x32_bf16(a_kv[rt], bv0[ct], aV[rt][ct], 0, 0, 0);
            }
        }
#pragma unroll
        for (int ct = 0; ct < 4; ++ct) { bq0[ct] = bq1[ct]; bk0[ct] = bk1[ct]; bv0[ct] = bv1[ct]; }
    }
    __syncthreads();   // all reads of sQ/sKV complete before in-place writes
#pragma unroll
    for (int ct = 0; ct < 4; ++ct) {
        const int col = wv * 64 + ct * 16 + m;
        const float bbq = bq[col], bbk = bk[col], bbv = bv[col];
#pragma unroll
        for (int rt = 0; rt < RQ; ++rt)
#pragma unroll
            for (int r = 0; r < 4; ++r) {
                const int row = rt * 16 + g * 4 + r;
                *(ushort*)(sQ + SWZ(row, 2 * col)) = f2bu(aQ[rt][ct][r] + bbq);
            }
#pragma unroll
        for (int rt = 0; rt < RK; ++rt)
#pragma unroll
            for (int r = 0; r < 4; ++r) {
                const int row = rt * 16 + g * 4 + r;
                *(ushort*)(sK  + SWZ(row, 2 * col)) = f2bu(aK[rt][ct][r] + bbk);
                *(ushort*)(sKV + SWZ(row, 2 * col)) = f2bu(aV[rt][ct][r] + bbv);
            }
    }
}

// ---------------- fused MAB: 1 block / batch element, 512 threads = 8 waves ----------------
template <int SQ, int SK, bool PREQ, bool KIN_BF16, bool OUT_BF16, bool MEANPOOL>
__global__ __launch_bounds__(512) void mab2(
    const float* __restrict__ Qin, const float* __restrict__ Q0,
    const void* __restrict__ Kin,
    const ushort* __restrict__ WtQ, const float* __restrict__ bq,
    const ushort* __restrict__ WtK, const float* __restrict__ bk,
    const ushort* __restrict__ WtV, const float* __restrict__ bv,
    const ushort* __restrict__ WtO, const float* __restrict__ bo,
    const float* __restrict__ g0, const float* __restrict__ b0,
    const float* __restrict__ g1, const float* __restrict__ b1,
    void* __restrict__ out)
{
    constexpr int SKP = SK + 1;
    __shared__ __align__(16) char smem[2 * SK * 1024 + SQ * 1024 + 8 * SQ * SKP * 4];
    char* sK    = smem;                       // K proj [SK][512] swizzled
    char* sV    = smem + SK * 1024;           // staged Kin, then V proj [SK][512]
    char* sQm   = smem + 2 * SK * 1024;       // Q -> O -> ln0(O) [SQ][512]
    float* sSal = (float*)(smem + 2 * SK * 1024 + SQ * 1024);  // per-wave scores
    char* sT    = smem;                       // FFN out [SQ][512] (sK+sV regions dead)

    const int tid = threadIdx.x, lane = tid & 63, wv = tid >> 6;
    const int b = blockIdx.x;

    // ---- stage Kin[b] -> sV (bf16, swizzled) ----
    if constexpr (KIN_BF16) {
        const ushort* kin = (const ushort*)Kin + (size_t)b * SK * D;
        for (int c = tid; c < SK * (D / 4); c += 512) {
            const int row = c >> 7, k4 = (c & 127) << 2;
            *(s4v*)(sV + SWZ(row, k4 * 2)) = *(const s4v*)(kin + (row << 9) + k4);
        }
    } else {
        const float* kin = (const float*)Kin + (size_t)b * SK * D;
        for (int c = tid; c < SK * (D / 4); c += 512) {
            const int row = c >> 7, k4 = (c & 127) << 2;
            const float4 v = *(const float4*)(kin + (row << 9) + k4);
            s4v o = {(short)f2bu(v.x), (short)f2bu(v.y), (short)f2bu(v.z), (short)f2bu(v.w)};
            *(s4v*)(sV + SWZ(row, k4 * 2)) = o;
        }
    }
    // ---- stage Q source -> sQm ----
    {
        const float* qsrc = PREQ ? Q0 : (Qin + (size_t)b * SQ * D);
        for (int c = tid; c < SQ * (D / 4); c += 512) {
            const int row = c >> 7, k4 = (c & 127) << 2;
            const float4 v = *(const float4*)(qsrc + (row << 9) + k4);
            s4v o = {(short)f2bu(v.x), (short)f2bu(v.y), (short)f2bu(v.z), (short)f2bu(v.w)};
            *(s4v*)(sQm + SWZ(row, k4 * 2)) = o;
        }
    }
    __syncthreads();

    if constexpr (!PREQ) {
        // Q + K + V projections in one register-pipelined k-loop
        gemm_triple_ws<SQ, SK>(sQm, WtQ, bq, sV, WtK, bk, WtV, bv, sK, lane, wv);
    } else {
        gemm_dual_ws<SK>(sV, WtK, bk, WtV, bv, sK, sV, lane, wv);
    }
    __syncthreads();

    // ---- attention: wave wv <-> head wv (each wave owns its 64 head-cols) ----
    {
        const int h64 = wv * 64;
        float* myS = sSal + wv * SQ * SKP;
        const float scale = 0.044194173824159216f;   // 1/sqrt(512)
        // scores
#pragma unroll
        for (int o = 0; o < SQ * SK / 64; ++o) {
            const int idx = o * 64 + lane;
            const int q = idx / SK, k = idx % SK;
            float s = 0.f;
#pragma unroll
            for (int dd = 0; dd < 64; dd += 8) {
                const s8v aq = *(const s8v*)(sQm + SWZ(q, 2 * (h64 + dd)));
                const s8v ak = *(const s8v*)(sK + SWZ(k, 2 * (h64 + dd)));
#pragma unroll
                for (int e = 0; e < 8; ++e)
                    s = fmaf(bu2f((ushort)aq[e]), bu2f((ushort)ak[e]), s);
            }
            myS[q * SKP + k] = s * scale;
        }
        __syncthreads();
        // softmax (lane q owns row q; SK <= 32 serial)
        if (lane < SQ) {
            float* row = myS + lane * SKP;
            float mx = row[0];
#pragma unroll
            for (int k = 1; k < SK; ++k) mx = fmaxf(mx, row[k]);
            float sum = 0.f;
#pragma unroll
            for (int k = 0; k < SK; ++k) { const float e = __expf(row[k] - mx); row[k] = e; sum += e; }
            const float inv = 1.f / sum;
#pragma unroll
            for (int k = 0; k < SK; ++k) row[k] *= inv;
        }
        __syncthreads();
        // PV + residual: lane owns d0 = lane within the head
        float acc[SQ];
#pragma unroll
        for (int q = 0; q < SQ; ++q) acc[q] = 0.f;
#pragma unroll 4
        for (int k = 0; k < SK; ++k) {
            const float v = bu2f(*(const ushort*)(sV + SWZ(k, 2 * (h64 + lane))));
#pragma unroll
            for (int q = 0; q < SQ; ++q) acc[q] = fmaf(myS[q * SKP + k], v, acc[q]);
        }
#pragma unroll
        for (int q = 0; q < SQ; ++q) {
            ushort* p = (ushort*)(sQm + SWZ(q, 2 * (h64 + lane)));
            *p = f2bu(bu2f(*p) + acc[q]);
        }
    }
    __syncthreads();

    // ---- ln0 in place on sQm ----
    for (int i = wv; i < SQ; i += 8) {
        float v[8];
#pragma unroll
        for (int j = 0; j < 8; ++j) v[j] = bu2f(*(const ushort*)(sQm + SWZ(i, 2 * (lane + 64 * j))));
        float s = 0.f;
#pragma unroll
        for (int j = 0; j < 8; ++j) s += v[j];
        s = wave_sum(s);
        const float mu = s * (1.f / 512.f);
        float q2 = 0.f;
#pragma unroll
        for (int j = 0; j < 8; ++j) { const float t = v[j] - mu; q2 = fmaf(t, t, q2); }
        q2 = wave_sum(q2);
        const float inv = rsqrtf(q2 * (1.f / 512.f) + 1e-5f);
#pragma unroll
        for (int j = 0; j < 8; ++j) {
            const int d0 = lane + 64 * j;
            *(ushort*)(sQm + SWZ(i, 2 * d0)) = f2bu((v[j] - mu) * inv * g0[d0] + b0[d0]);
        }
    }
    __syncthreads();

    // ---- FFN: sT = ln0(O) @ Wo + bo ----
    gemm_ws<SQ>(sQm, WtO, bo, sT, lane, wv);
    __syncthreads();

    // ---- U = O + relu(T); ln1; output ----
    for (int i = wv; i < SQ; i += 8) {
        float v[8];
#pragma unroll
        for (int j = 0; j < 8; ++j) {
            const int d0 = lane + 64 * j;
            v[j] = bu2f(*(const ushort*)(sQm + SWZ(i, 2 * d0))) +
                   fmaxf(bu2f(*(const ushort*)(sT + SWZ(i, 2 * d0))), 0.f);
        }
        float s = 0.f;
#pragma unroll
        for (int j = 0; j < 8; ++j) s += v[j];
        s = wave_sum(s);
        const float mu = s * (1.f / 512.f);
        float q2 = 0.f;
#pragma unroll
        for (int j = 0; j < 8; ++j) { const float t = v[j] - mu; q2 = fmaf(t, t, q2); }
        q2 = wave_sum(q2);
        const float inv = rsqrtf(q2 * (1.f / 512.f) + 1e-5f);
        if constexpr (MEANPOOL) {
#pragma unroll
            for (int j = 0; j < 8; ++j) {
                const int d0 = lane + 64 * j;
                *(ushort*)(sQm + SWZ(i, 2 * d0)) = f2bu((v[j] - mu) * inv * g1[d0] + b1[d0]);
            }
        } else if constexpr (OUT_BF16) {
            ushort* ob = (ushort*)out + (size_t)b * SQ * D;
#pragma unroll
            for (int j = 0; j < 8; ++j) {
                const int d0 = lane + 64 * j;
                ob[i * D + d0] = f2bu((v[j] - mu) * inv * g1[d0] + b1[d0]);
            }
        } else {
            float* ob = (float*)out + (size_t)b * SQ * D;
#pragma unroll
            for (int j = 0; j < 8; ++j) {
                const int d0 = lane + 64 * j;
                ob[i * D + d0] = (v[j] - mu) * inv * g1[d0] + b1[d0];
            }
        }
    }
    if constexpr (MEANPOOL) {
        __syncthreads();
        float s = 0.f;
#pragma unroll 8
        for (int i = 0; i < SQ; ++i) s += bu2f(*(const ushort*)(sQm + SWZ(i, 2 * tid)));
        ((float*)out)[(size_t)b * D + tid] = s * (1.f / SQ);
    }
}

extern "C" void kernel_launch(void* const* d_in, const int* in_sizes, int n_in,
                              void* d_out, int out_size, void* d_ws, size_t ws_size,
                              hipStream_t stream) {
    (void)in_sizes; (void)n_in; (void)out_size; (void)ws_size;

    const float* x     = (const float*)d_in[0];
    const float* I     = (const float*)d_in[1];
    const float* W0    = (const float*)d_in[2];
    const float* bqkv0 = (const float*)d_in[3];
    const float* Wo0   = (const float*)d_in[4];
    const float* bo0   = (const float*)d_in[5];
    const float* g00   = (const float*)d_in[6];
    const float* b00   = (const float*)d_in[7];
    const float* g01   = (const float*)d_in[8];
    const float* b01   = (const float*)d_in[9];
    const float* W1    = (const float*)d_in[10];
    const float* bqkv1 = (const float*)d_in[11];
    const float* Wo1   = (const float*)d_in[12];
    const float* bo1   = (const float*)d_in[13];
    const float* g10   = (const float*)d_in[14];
    const float* b10   = (const float*)d_in[15];
    const float* g11   = (const float*)d_in[16];
    const float* b11   = (const float*)d_in[17];

    const float* Wq0 = W0;     const float* Wk0 = W0 + D * D;  const float* Wv0 = W0 + 2 * D * D;
    const float* bq0 = bqkv0;  const float* bk0 = bqkv0 + D;   const float* bv0 = bqkv0 + 2 * D;
    const float* Wq1 = W1;     const float* Wk1 = W1 + D * D;  const float* Wv1 = W1 + 2 * D * D;
    const float* bq1 = bqkv1;  const float* bk1 = bqkv1 + D;   const float* bv1 = bqkv1 + 2 * D;

    char* ws = (char*)d_ws;
    float*  Q0  = (float*)ws;                                   // 32 KB
    ushort* Wt  = (ushort*)(ws + 32768);                        // 7 x 512 KB bf16
    ushort* Hm  = (ushort*)(ws + 32768 + 7 * 524288);           // B*16*512 bf16 = 32 MB
    float*  Xb  = (float*)(ws + 32768 + 7 * 524288 + (size_t)BATCH * MIND * D * 2);  // 128 MB

    ushort* WtK0 = Wt + 0 * 262144;
    ushort* WtV0 = Wt + 1 * 262144;
    ushort* WtO0 = Wt + 2 * 262144;
    ushort* WtQ1 = Wt + 3 * 262144;
    ushort* WtK1 = Wt + 4 * 262144;
    ushort* WtV1 = Wt + 5 * 262144;
    ushort* WtO1 = Wt + 6 * 262144;

    dim3 tg(16, 16);
    wtrans<<<tg, 256, 0, stream>>>(Wk0, WtK0);
    wtrans<<<tg, 256, 0, stream>>>(Wv0, WtV0);
    wtrans<<<tg, 256, 0, stream>>>(Wo0, WtO0);
    wtrans<<<tg, 256, 0, stream>>>(Wq1, WtQ1);
    wtrans<<<tg, 256, 0, stream>>>(Wk1, WtK1);
    wtrans<<<tg, 256, 0, stream>>>(Wv1, WtV1);
    wtrans<<<tg, 256, 0, stream>>>(Wo1, WtO1);
    q0_kernel<<<MIND, 256, 0, stream>>>(I, Wq0, bq0, Q0);

    // ISAB 1: Hm = mab0(I, x); h1(Xb) = mab1(x, Hm)
    mab2<MIND, SEQ, true, false, true, false><<<BATCH, 512, 0, stream>>>(
        nullptr, Q0, x, nullptr, nullptr, WtK0, bk0, WtV0, bv0, WtO0, bo0,
        g00, b00, g01, b01, Hm);
    mab2<SEQ, MIND, false, true, false, false><<<BATCH, 512, 0, stream>>>(
        x, nullptr, Hm, WtQ1, bq1, WtK1, bk1, WtV1, bv1, WtO1, bo1,
        g10, b10, g11, b11, Xb);

    // ISAB 2: Hm = mab0(I, h1); out = meanpool(mab1(h1, Hm))
    mab2<MIND, SEQ, true, false, true, false><<<BATCH, 512, 0, stream>>>(
        nullptr, Q0, Xb, nullptr, nullptr, WtK0, bk0, WtV0, bv0, WtO0, bo0,
        g00, b00, g01, b01, Hm);
    mab2<SEQ, MIND, false, true, false, true><<<BATCH, 512, 0, stream>>>(
        Xb, nullptr, Hm, WtQ1, bq1, WtK1, bk1, WtV1, bv1, WtO1, bo1,
        g10, b10, g11, b11, d_out);
}

// Round 5
// 1633.675 us; speedup vs baseline: 6.6790x; 1.4485x over previous
//
#include <hip/hip_runtime.h>
#include <hip/hip_bf16.h>

#define D 512
#define BATCH 2048
#define SEQ 32
#define MIND 16

typedef __hip_bfloat16 bf16;
typedef __attribute__((ext_vector_type(8))) short s8v;   // 8 bf16 (MFMA A/B frag)
typedef __attribute__((ext_vector_type(4))) short s4v;
typedef __attribute__((ext_vector_type(4))) float f4v;   // MFMA C/D frag

// byte-offset swizzle for [row][512]-bf16 LDS tiles (row stride 1024B):
// XOR byte bits 4-6 with row&7 -> conflict-free b128 column reads
#define SWZ(row, kb) (((row) << 10) + ((kb) ^ (((row) & 7) << 4)))

__device__ __forceinline__ ushort f2bu(float f) {
    bf16 h = __float2bfloat16(f); ushort u; __builtin_memcpy(&u, &h, 2); return u;
}
__device__ __forceinline__ float bu2f(ushort u) {
    unsigned x = ((unsigned)u) << 16; float f; __builtin_memcpy(&f, &x, 4); return f;
}

__device__ __forceinline__ float wave_sum(float v) {
#pragma unroll
    for (int off = 32; off >= 1; off >>= 1) v += __shfl_xor(v, off, 64);
    return v;
}

// ---------------- weight pre-transpose: W[k][n] fp32 -> Wt[n][k] bf16 ----------------
__global__ __launch_bounds__(256) void wtrans(const float* __restrict__ W,
                                              ushort* __restrict__ Wt) {
    __shared__ float t[32][33];
    const int k0 = blockIdx.x * 32, n0 = blockIdx.y * 32;
    const int lx = threadIdx.x & 31, ly = threadIdx.x >> 5;
    for (int i = ly; i < 32; i += 8) t[i][lx] = W[(size_t)(k0 + i) * D + n0 + lx];
    __syncthreads();
    for (int i = ly; i < 32; i += 8)
        Wt[(size_t)(n0 + i) * D + k0 + lx] = f2bu(t[lx][i]);
}

// ---------------- Q0b[16][512] = bf16(I @ Wq0 + bq0) (batch-independent) ----------------
__global__ __launch_bounds__(256) void q0_kernel(
    const float* __restrict__ I, const float* __restrict__ Wq,
    const float* __restrict__ bq, ushort* __restrict__ Q0b)
{
    const int q = blockIdx.x;
    const int c = threadIdx.x;
    float a0 = 0.f, a1 = 0.f;
    for (int k = 0; k < D; ++k) {
        const float iv = I[q * D + k];
        a0 = fmaf(iv, Wq[(size_t)k * D + c], a0);
        a1 = fmaf(iv, Wq[(size_t)k * D + c + 256], a1);
    }
    Q0b[q * D + c]       = f2bu(a0 + bq[c]);
    Q0b[q * D + c + 256] = f2bu(a1 + bq[c + 256]);
}

// ---------------- fp32 -> bf16 convert ----------------
__global__ __launch_bounds__(256) void conv_bf16(const float* __restrict__ x,
                                                 ushort* __restrict__ xb, long n4) {
    for (long i = (long)blockIdx.x * 256 + threadIdx.x; i < n4; i += (long)gridDim.x * 256) {
        const float4 v = ((const float4*)x)[i];
        s4v o = {(short)f2bu(v.x), (short)f2bu(v.y), (short)f2bu(v.z), (short)f2bu(v.w)};
        ((s4v*)xb)[i] = o;
    }
}

// ---------------- batched GEMM: C[M,512] = A[M,512](bf16) @ Wt[512,512] + bias ----------------
// BM=64 rows/block, full K=512 in LDS (64KB). 512 thr = 8 waves; wave wv owns cols
// [wv*64, wv*64+64). RESFUSE: C = A_row + relu(acc+bias)  (FFN residual; valid since K==N).
// launch_bounds(512,4): cap 128 VGPR -> 2 blocks/CU (4 waves/SIMD) for latency hiding.
template <bool RESFUSE>
__global__ __launch_bounds__(512, 4) void gemm512(
    const ushort* __restrict__ Ab, const ushort* __restrict__ Wt,
    const float* __restrict__ bias, ushort* __restrict__ Cb)
{
    __shared__ __align__(16) char sA[64 * 1024];
    const int tid = threadIdx.x, lane = tid & 63, wv = tid >> 6;
    const size_t m0 = (size_t)blockIdx.x * 64;

    // stage A (bf16, swizzled)
    for (int c = tid; c < 64 * 128; c += 512) {
        const int row = c >> 7, k4 = (c & 127) << 2;
        *(s4v*)(sA + SWZ(row, k4 * 2)) = *(const s4v*)(Ab + (m0 + row) * D + k4);
    }
    __syncthreads();

    constexpr int RT = 4;
    f4v acc[RT][4];
#pragma unroll
    for (int i = 0; i < RT; ++i)
#pragma unroll
        for (int j = 0; j < 4; ++j) acc[i][j] = (f4v){0.f, 0.f, 0.f, 0.f};
    const int m = lane & 15, g = lane >> 4;
    const int swm = (m & 7) << 4;
    const ushort* Bp = Wt + ((size_t)(wv * 64 + m) << 9) + 8 * g;

#pragma unroll
    for (int k0 = 0; k0 < 512; k0 += 32) {
        s8v bfr[4];
#pragma unroll
        for (int ct = 0; ct < 4; ++ct) bfr[ct] = *(const s8v*)(Bp + ct * 8192 + k0);
        const int kb = 2 * (k0 + 8 * g);
        s8v a[RT];
#pragma unroll
        for (int rt = 0; rt < RT; ++rt)
            a[rt] = *(const s8v*)(sA + ((rt * 16 + m) << 10) + (kb ^ swm));
#pragma unroll
        for (int ct = 0; ct < 4; ++ct)
#pragma unroll
            for (int rt = 0; rt < RT; ++rt)
                acc[rt][ct] = __builtin_amdgcn_mfma_f32_16x16x32_bf16(a[rt], bfr[ct], acc[rt][ct], 0, 0, 0);
    }

#pragma unroll
    for (int ct = 0; ct < 4; ++ct) {
        const int col = wv * 64 + ct * 16 + m;
        const float bb = bias[col];
#pragma unroll
        for (int rt = 0; rt < RT; ++rt)
#pragma unroll
            for (int r = 0; r < 4; ++r) {
                const int row = rt * 16 + g * 4 + r;
                float v = acc[rt][ct][r] + bb;
                if (RESFUSE)
                    v = bu2f(*(const ushort*)(sA + SWZ(row, 2 * col))) + fmaxf(v, 0.f);
                Cb[(m0 + row) * D + col] = f2bu(v);
            }
    }
}

// ---------------- fused attention + ln0 (no GEMMs): 1 block / batch element ----------------
// O = Q + softmax(QK^T/sqrt(512)) V  per 8 heads (wave=head), then ln0 -> out bf16.
template <int SQ, int SK, bool QSHARED>
__global__ __launch_bounds__(512) void attn(
    const ushort* __restrict__ Qb, const ushort* __restrict__ Kb,
    const ushort* __restrict__ Vb,
    const float* __restrict__ gg, const float* __restrict__ bb,
    ushort* __restrict__ outp)
{
    constexpr int SKP = SK + 1;
    __shared__ __align__(16) char smem[2 * SK * 1024 + SQ * 1024 + 8 * SQ * SKP * 4];
    char* sK    = smem;
    char* sV    = smem + SK * 1024;
    char* sQm   = smem + 2 * SK * 1024;
    float* sSal = (float*)(smem + 2 * SK * 1024 + SQ * 1024);

    const int tid = threadIdx.x, lane = tid & 63, wv = tid >> 6;
    const int b = blockIdx.x;

    const ushort* kin = Kb + (size_t)b * SK * D;
    const ushort* vin = Vb + (size_t)b * SK * D;
    const ushort* qin = Qb + (QSHARED ? 0 : (size_t)b * SQ * D);

    for (int c = tid; c < SK * 128; c += 512) {
        const int row = c >> 7, k4 = (c & 127) << 2;
        *(s4v*)(sK + SWZ(row, k4 * 2)) = *(const s4v*)(kin + (row << 9) + k4);
        *(s4v*)(sV + SWZ(row, k4 * 2)) = *(const s4v*)(vin + (row << 9) + k4);
    }
    for (int c = tid; c < SQ * 128; c += 512) {
        const int row = c >> 7, k4 = (c & 127) << 2;
        *(s4v*)(sQm + SWZ(row, k4 * 2)) = *(const s4v*)(qin + (row << 9) + k4);
    }
    __syncthreads();

    // ---- attention: wave wv <-> head wv ----
    {
        const int h64 = wv * 64;
        float* myS = sSal + wv * SQ * SKP;
        const float scale = 0.044194173824159216f;   // 1/sqrt(512)
#pragma unroll
        for (int o = 0; o < SQ * SK / 64; ++o) {
            const int idx = o * 64 + lane;
            const int q = idx / SK, k = idx % SK;
            float s = 0.f;
#pragma unroll
            for (int dd = 0; dd < 64; dd += 8) {
                const s8v aq = *(const s8v*)(sQm + SWZ(q, 2 * (h64 + dd)));
                const s8v ak = *(const s8v*)(sK + SWZ(k, 2 * (h64 + dd)));
#pragma unroll
                for (int e = 0; e < 8; ++e)
                    s = fmaf(bu2f((ushort)aq[e]), bu2f((ushort)ak[e]), s);
            }
            myS[q * SKP + k] = s * scale;
        }
        __syncthreads();
        if (lane < SQ) {
            float* row = myS + lane * SKP;
            float mx = row[0];
#pragma unroll
            for (int k = 1; k < SK; ++k) mx = fmaxf(mx, row[k]);
            float sum = 0.f;
#pragma unroll
            for (int k = 0; k < SK; ++k) { const float e = __expf(row[k] - mx); row[k] = e; sum += e; }
            const float inv = 1.f / sum;
#pragma unroll
            for (int k = 0; k < SK; ++k) row[k] *= inv;
        }
        __syncthreads();
        float acc[SQ];
#pragma unroll
        for (int q = 0; q < SQ; ++q) acc[q] = 0.f;
#pragma unroll 4
        for (int k = 0; k < SK; ++k) {
            const float v = bu2f(*(const ushort*)(sV + SWZ(k, 2 * (h64 + lane))));
#pragma unroll
            for (int q = 0; q < SQ; ++q) acc[q] = fmaf(myS[q * SKP + k], v, acc[q]);
        }
#pragma unroll
        for (int q = 0; q < SQ; ++q) {
            ushort* p = (ushort*)(sQm + SWZ(q, 2 * (h64 + lane)));
            *p = f2bu(bu2f(*p) + acc[q]);
        }
    }
    __syncthreads();

    // ---- ln0 -> global bf16 ----
    for (int i = wv; i < SQ; i += 8) {
        float v[8];
#pragma unroll
        for (int j = 0; j < 8; ++j) v[j] = bu2f(*(const ushort*)(sQm + SWZ(i, 2 * (lane + 64 * j))));
        float s = 0.f;
#pragma unroll
        for (int j = 0; j < 8; ++j) s += v[j];
        s = wave_sum(s);
        const float mu = s * (1.f / 512.f);
        float q2 = 0.f;
#pragma unroll
        for (int j = 0; j < 8; ++j) { const float t = v[j] - mu; q2 = fmaf(t, t, q2); }
        q2 = wave_sum(q2);
        const float inv = rsqrtf(q2 * (1.f / 512.f) + 1e-5f);
        ushort* ob = outp + ((size_t)b * SQ + i) * D;
#pragma unroll
        for (int j = 0; j < 8; ++j) {
            const int d0 = lane + 64 * j;
            ob[d0] = f2bu((v[j] - mu) * inv * gg[d0] + bb[d0]);
        }
    }
}

// ---------------- row-LN (+ optional mean pool over 32 rows) ----------------
template <bool MEAN>
__global__ __launch_bounds__(512) void lnout(
    const ushort* __restrict__ U, const float* __restrict__ gg,
    const float* __restrict__ bb, void* __restrict__ outp)
{
    const int tid = threadIdx.x, lane = tid & 63, wv = tid >> 6;
    if constexpr (!MEAN) {
        const size_t row = (size_t)blockIdx.x * 8 + wv;
        const ushort* u = U + row * D;
        float v[8];
#pragma unroll
        for (int j = 0; j < 8; ++j) v[j] = bu2f(u[lane + 64 * j]);
        float s = 0.f;
#pragma unroll
        for (int j = 0; j < 8; ++j) s += v[j];
        s = wave_sum(s);
        const float mu = s * (1.f / 512.f);
        float q2 = 0.f;
#pragma unroll
        for (int j = 0; j < 8; ++j) { const float t = v[j] - mu; q2 = fmaf(t, t, q2); }
        q2 = wave_sum(q2);
        const float inv = rsqrtf(q2 * (1.f / 512.f) + 1e-5f);
        ushort* o = (ushort*)outp + row * D;
#pragma unroll
        for (int j = 0; j < 8; ++j) {
            const int d0 = lane + 64 * j;
            o[d0] = f2bu((v[j] - mu) * inv * gg[d0] + bb[d0]);
        }
    } else {
        __shared__ float sP[8][512];
        const size_t b = blockIdx.x;
        float a[8];
#pragma unroll
        for (int j = 0; j < 8; ++j) a[j] = 0.f;
        for (int i = wv; i < 32; i += 8) {
            const ushort* u = U + ((size_t)b * 32 + i) * D;
            float v[8];
#pragma unroll
            for (int j = 0; j < 8; ++j) v[j] = bu2f(u[lane + 64 * j]);
            float s = 0.f;
#pragma unroll
            for (int j = 0; j < 8; ++j) s += v[j];
            s = wave_sum(s);
            const float mu = s * (1.f / 512.f);
            float q2 = 0.f;
#pragma unroll
            for (int j = 0; j < 8; ++j) { const float t = v[j] - mu; q2 = fmaf(t, t, q2); }
            q2 = wave_sum(q2);
            const float inv = rsqrtf(q2 * (1.f / 512.f) + 1e-5f);
#pragma unroll
            for (int j = 0; j < 8; ++j) {
                const int d0 = lane + 64 * j;
                a[j] += (v[j] - mu) * inv * gg[d0] + bb[d0];
            }
        }
#pragma unroll
        for (int j = 0; j < 8; ++j) sP[wv][lane + 64 * j] = a[j];
        __syncthreads();
        float s = 0.f;
#pragma unroll
        for (int w = 0; w < 8; ++w) s += sP[w][tid];
        ((float*)outp)[b * D + tid] = s * (1.f / 32.f);
    }
}

extern "C" void kernel_launch(void* const* d_in, const int* in_sizes, int n_in,
                              void* d_out, int out_size, void* d_ws, size_t ws_size,
                              hipStream_t stream) {
    (void)in_sizes; (void)n_in; (void)out_size; (void)ws_size;

    const float* x     = (const float*)d_in[0];
    const float* I     = (const float*)d_in[1];
    const float* W0    = (const float*)d_in[2];
    const float* bqkv0 = (const float*)d_in[3];
    const float* Wo0   = (const float*)d_in[4];
    const float* bo0   = (const float*)d_in[5];
    const float* g00   = (const float*)d_in[6];
    const float* b00   = (const float*)d_in[7];
    const float* g01   = (const float*)d_in[8];
    const float* b01   = (const float*)d_in[9];
    const float* W1    = (const float*)d_in[10];
    const float* bqkv1 = (const float*)d_in[11];
    const float* Wo1   = (const float*)d_in[12];
    const float* bo1   = (const float*)d_in[13];
    const float* g10   = (const float*)d_in[14];
    const float* b10   = (const float*)d_in[15];
    const float* g11   = (const float*)d_in[16];
    const float* b11   = (const float*)d_in[17];

    const float* Wq0 = W0;     const float* Wk0 = W0 + D * D;  const float* Wv0 = W0 + 2 * D * D;
    const float* bq0 = bqkv0;  const float* bk0 = bqkv0 + D;   const float* bv0 = bqkv0 + 2 * D;
    const float* Wq1 = W1;     const float* Wk1 = W1 + D * D;  const float* Wv1 = W1 + 2 * D * D;
    const float* bq1 = bqkv1;  const float* bk1 = bqkv1 + D;   const float* bv1 = bqkv1 + 2 * D;

    // ---- workspace layout (~228 MB) ----
    char* ws = (char*)d_ws;
    ushort* Q0b = (ushort*)ws;                    // 16 KB (pad to 32 KB)
    ushort* Wt  = (ushort*)(ws + 32768);          // 7 x 512 KB
    char* p = ws + 32768 + 7 * 524288;
    ushort* bufA = (ushort*)p;            p += (size_t)64 << 20;   // x_bf16 / X1ln / Xout
    ushort* bufB = (ushort*)p;            p += (size_t)64 << 20;   // Kb -> Qb -> U1
    ushort* bufDE = (ushort*)p;           p += (size_t)64 << 20;   // Vb -> U0/K1(lo) V1(hi)
    ushort* bufF = (ushort*)p;            p += (size_t)32 << 20;   // Hm_ln -> Hm
    ushort* bufD = bufDE;                                  // 32 MB lo half
    ushort* bufE = bufDE + ((size_t)16 << 20);             // 32 MB hi half (ushort elems)

    ushort* WtK0 = Wt + 0 * 262144;
    ushort* WtV0 = Wt + 1 * 262144;
    ushort* WtO0 = Wt + 2 * 262144;
    ushort* WtQ1 = Wt + 3 * 262144;
    ushort* WtK1 = Wt + 4 * 262144;
    ushort* WtV1 = Wt + 5 * 262144;
    ushort* WtO1 = Wt + 6 * 262144;

    dim3 tg(16, 16);
    wtrans<<<tg, 256, 0, stream>>>(Wk0, WtK0);
    wtrans<<<tg, 256, 0, stream>>>(Wv0, WtV0);
    wtrans<<<tg, 256, 0, stream>>>(Wo0, WtO0);
    wtrans<<<tg, 256, 0, stream>>>(Wq1, WtQ1);
    wtrans<<<tg, 256, 0, stream>>>(Wk1, WtK1);
    wtrans<<<tg, 256, 0, stream>>>(Wv1, WtV1);
    wtrans<<<tg, 256, 0, stream>>>(Wo1, WtO1);
    q0_kernel<<<MIND, 256, 0, stream>>>(I, Wq0, bq0, Q0b);
    conv_bf16<<<4096, 256, 0, stream>>>(x, bufA, (long)BATCH * SEQ * D / 4);

    constexpr int GM_BS = BATCH * SEQ / 64;   // 1024 (M = 65536)
    constexpr int GM_BM = BATCH * MIND / 64;  // 512  (M = 32768)

    for (int isab = 0; isab < 2; ++isab) {
        // mab0: K,V proj from X; attention vs Q0; FFN; ln1 -> Hm
        gemm512<false><<<GM_BS, 512, 0, stream>>>(bufA, WtK0, bk0, bufB);
        gemm512<false><<<GM_BS, 512, 0, stream>>>(bufA, WtV0, bv0, bufDE);
        attn<MIND, SEQ, true><<<BATCH, 512, 0, stream>>>(Q0b, bufB, bufDE, g00, b00, bufF);
        gemm512<true><<<GM_BM, 512, 0, stream>>>(bufF, WtO0, bo0, bufD);            // U0
        lnout<false><<<BATCH * MIND / 8, 512, 0, stream>>>(bufD, g01, b01, bufF);   // Hm
        // mab1: Q proj from X; K,V proj from Hm; attention; FFN; ln1
        gemm512<false><<<GM_BS, 512, 0, stream>>>(bufA, WtQ1, bq1, bufB);           // Qb
        gemm512<false><<<GM_BM, 512, 0, stream>>>(bufF, WtK1, bk1, bufD);           // K1
        gemm512<false><<<GM_BM, 512, 0, stream>>>(bufF, WtV1, bv1, bufE);           // V1
        attn<SEQ, MIND, false><<<BATCH, 512, 0, stream>>>(bufB, bufD, bufE, g10, b10, bufA);
        gemm512<true><<<GM_BS, 512, 0, stream>>>(bufA, WtO1, bo1, bufB);            // U1
        if (isab == 0)
            lnout<false><<<BATCH * SEQ / 8, 512, 0, stream>>>(bufB, g11, b11, bufA);
        else
            lnout<true><<<BATCH, 512, 0, stream>>>(bufB, g11, b11, d_out);
    }
}

// Round 6
// 1501.502 us; speedup vs baseline: 7.2669x; 1.0880x over previous
//
#include <hip/hip_runtime.h>
#include <hip/hip_bf16.h>

#define D 512
#define BATCH 2048
#define SEQ 32
#define MIND 16

typedef __hip_bfloat16 bf16;
typedef __attribute__((ext_vector_type(8))) short s8v;   // 8 bf16 (MFMA A/B frag)
typedef __attribute__((ext_vector_type(4))) short s4v;
typedef __attribute__((ext_vector_type(4))) float f4v;   // MFMA C/D frag

// byte-offset swizzle for [row][512]-bf16 LDS tiles (row stride 1024B):
// XOR byte bits 4-6 with row&7 -> conflict-free b128 column reads
#define SWZ(row, kb) (((row) << 10) + ((kb) ^ (((row) & 7) << 4)))

__device__ __forceinline__ ushort f2bu(float f) {
    bf16 h = __float2bfloat16(f); ushort u; __builtin_memcpy(&u, &h, 2); return u;
}
__device__ __forceinline__ float bu2f(ushort u) {
    unsigned x = ((unsigned)u) << 16; float f; __builtin_memcpy(&f, &x, 4); return f;
}

__device__ __forceinline__ float wave_sum(float v) {
#pragma unroll
    for (int off = 32; off >= 1; off >>= 1) v += __shfl_xor(v, off, 64);
    return v;
}

// ---------------- weight pre-transpose: 7x W[k][n] fp32 -> Wt[n][k] bf16 ----------------
struct WPtrs { const float* s[7]; };

__global__ __launch_bounds__(256) void wtrans7(WPtrs wp, ushort* __restrict__ Wt) {
    const float* W = wp.s[blockIdx.z];
    ushort* dst = Wt + (size_t)blockIdx.z * 262144;
    __shared__ float t[32][33];
    const int k0 = blockIdx.x * 32, n0 = blockIdx.y * 32;
    const int lx = threadIdx.x & 31, ly = threadIdx.x >> 5;
    for (int i = ly; i < 32; i += 8) t[i][lx] = W[(size_t)(k0 + i) * D + n0 + lx];
    __syncthreads();
    for (int i = ly; i < 32; i += 8)
        dst[(size_t)(n0 + i) * D + k0 + lx] = f2bu(t[lx][i]);
}

// ---------------- Q0b[16][512] = bf16(I @ Wq0 + bq0) (batch-independent) ----------------
__global__ __launch_bounds__(256) void q0_kernel(
    const float* __restrict__ I, const float* __restrict__ Wq,
    const float* __restrict__ bq, ushort* __restrict__ Q0b)
{
    const int q = blockIdx.x;
    const int c = threadIdx.x;
    float a0 = 0.f, a1 = 0.f;
    for (int k = 0; k < D; ++k) {
        const float iv = I[q * D + k];
        a0 = fmaf(iv, Wq[(size_t)k * D + c], a0);
        a1 = fmaf(iv, Wq[(size_t)k * D + c + 256], a1);
    }
    Q0b[q * D + c]       = f2bu(a0 + bq[c]);
    Q0b[q * D + c + 256] = f2bu(a1 + bq[c + 256]);
}

// ---------------- fp32 -> bf16 convert ----------------
__global__ __launch_bounds__(256) void conv_bf16(const float* __restrict__ x,
                                                 ushort* __restrict__ xb, long n4) {
    for (long i = (long)blockIdx.x * 256 + threadIdx.x; i < n4; i += (long)gridDim.x * 256) {
        const float4 v = ((const float4*)x)[i];
        s4v o = {(short)f2bu(v.x), (short)f2bu(v.y), (short)f2bu(v.z), (short)f2bu(v.w)};
        ((s4v*)xb)[i] = o;
    }
}

// ---------------- batched GEMM: C[M,512] = LN?(A[M,512]) @ Wt[512,512] + bias ----------------
// BM=64 rows/block, full K=512 in LDS (64KB). 512 thr = 8 waves; wave wv owns cols
// [wv*64, wv*64+64). LNA: LayerNorm(lng,lnb) applied to staged A rows (in LDS) before GEMM.
// RESFUSE: C = A_staged + relu(acc+bias)  (FFN residual on LN'd A; valid since K==N).
template <bool RESFUSE, bool LNA>
__global__ __launch_bounds__(512, 4) void gemm512(
    const ushort* __restrict__ Ab, const ushort* __restrict__ Wt,
    const float* __restrict__ bias,
    const float* __restrict__ lng, const float* __restrict__ lnb,
    ushort* __restrict__ Cb)
{
    __shared__ __align__(16) char sA[64 * 1024];
    const int tid = threadIdx.x, lane = tid & 63, wv = tid >> 6;
    const size_t m0 = (size_t)blockIdx.x * 64;

    // stage A (bf16, swizzled)
    for (int c = tid; c < 64 * 128; c += 512) {
        const int row = c >> 7, k4 = (c & 127) << 2;
        *(s4v*)(sA + SWZ(row, k4 * 2)) = *(const s4v*)(Ab + (m0 + row) * D + k4);
    }
    __syncthreads();

    if constexpr (LNA) {   // LayerNorm each staged row in place
        for (int i = wv; i < 64; i += 8) {
            float v[8];
#pragma unroll
            for (int j = 0; j < 8; ++j)
                v[j] = bu2f(*(const ushort*)(sA + SWZ(i, 2 * (lane + 64 * j))));
            float s = 0.f;
#pragma unroll
            for (int j = 0; j < 8; ++j) s += v[j];
            s = wave_sum(s);
            const float mu = s * (1.f / 512.f);
            float q2 = 0.f;
#pragma unroll
            for (int j = 0; j < 8; ++j) { const float t = v[j] - mu; q2 = fmaf(t, t, q2); }
            q2 = wave_sum(q2);
            const float inv = rsqrtf(q2 * (1.f / 512.f) + 1e-5f);
#pragma unroll
            for (int j = 0; j < 8; ++j) {
                const int d0 = lane + 64 * j;
                *(ushort*)(sA + SWZ(i, 2 * d0)) = f2bu((v[j] - mu) * inv * lng[d0] + lnb[d0]);
            }
        }
        __syncthreads();
    }

    constexpr int RT = 4;
    f4v acc[RT][4];
#pragma unroll
    for (int i = 0; i < RT; ++i)
#pragma unroll
        for (int j = 0; j < 4; ++j) acc[i][j] = (f4v){0.f, 0.f, 0.f, 0.f};
    const int m = lane & 15, g = lane >> 4;
    const int swm = (m & 7) << 4;
    const ushort* Bp = Wt + ((size_t)(wv * 64 + m) << 9) + 8 * g;

#pragma unroll
    for (int k0 = 0; k0 < 512; k0 += 32) {
        s8v bfr[4];
#pragma unroll
        for (int ct = 0; ct < 4; ++ct) bfr[ct] = *(const s8v*)(Bp + ct * 8192 + k0);
        const int kb = 2 * (k0 + 8 * g);
        s8v a[RT];
#pragma unroll
        for (int rt = 0; rt < RT; ++rt)
            a[rt] = *(const s8v*)(sA + ((rt * 16 + m) << 10) + (kb ^ swm));
#pragma unroll
        for (int ct = 0; ct < 4; ++ct)
#pragma unroll
            for (int rt = 0; rt < RT; ++rt)
                acc[rt][ct] = __builtin_amdgcn_mfma_f32_16x16x32_bf16(a[rt], bfr[ct], acc[rt][ct], 0, 0, 0);
    }

#pragma unroll
    for (int ct = 0; ct < 4; ++ct) {
        const int col = wv * 64 + ct * 16 + m;
        const float bb = bias[col];
#pragma unroll
        for (int rt = 0; rt < RT; ++rt)
#pragma unroll
            for (int r = 0; r < 4; ++r) {
                const int row = rt * 16 + g * 4 + r;
                float v = acc[rt][ct][r] + bb;
                if (RESFUSE)
                    v = bu2f(*(const ushort*)(sA + SWZ(row, 2 * col))) + fmaxf(v, 0.f);
                Cb[(m0 + row) * D + col] = f2bu(v);
            }
    }
}

// ---------------- per-(batch, head) attention core: O = Q_h + softmax(QK^T/sqrt(512)) V ----------------
// 1 wave per block, grid (BATCH, 8). Raw O out (no LN). LDS ~11-14KB -> many blocks/CU.
template <int SQ, int SK, bool QSHARED>
__global__ __launch_bounds__(64) void attn_core(
    const ushort* __restrict__ Qb, const ushort* __restrict__ Kb,
    const ushort* __restrict__ Vb, ushort* __restrict__ Ob)
{
    constexpr int RS = 72;   // row stride (ushorts) = 144B -> conflict-free-ish, 16B-aligned
    __shared__ __align__(16) ushort sQ[SQ * RS];
    __shared__ __align__(16) ushort sK[SK * RS];
    __shared__ __align__(16) ushort sV[SK * RS];
    __shared__ float sS[SQ][SK + 1];

    const int lane = threadIdx.x;
    const int b = blockIdx.x, h = blockIdx.y;
    const size_t qbase = (QSHARED ? (size_t)0 : (size_t)b * SQ * D) + h * 64;
    const size_t kbase = (size_t)b * SK * D + h * 64;

    for (int idx = lane; idx < SQ * 16; idx += 64) {
        const int r = idx >> 4, c4 = (idx & 15) << 2;
        *(s4v*)(sQ + r * RS + c4) = *(const s4v*)(Qb + qbase + (size_t)r * D + c4);
    }
    for (int idx = lane; idx < SK * 16; idx += 64) {
        const int r = idx >> 4, c4 = (idx & 15) << 2;
        *(s4v*)(sK + r * RS + c4) = *(const s4v*)(Kb + kbase + (size_t)r * D + c4);
        *(s4v*)(sV + r * RS + c4) = *(const s4v*)(Vb + kbase + (size_t)r * D + c4);
    }
    __syncthreads();

    const float scale = 0.044194173824159216f;   // 1/sqrt(512)
#pragma unroll
    for (int o = 0; o < SQ * SK / 64; ++o) {
        const int idx = o * 64 + lane;
        const int q = idx / SK, k = idx % SK;
        float s = 0.f;
#pragma unroll
        for (int dd = 0; dd < 64; dd += 8) {
            const s8v aq = *(const s8v*)(sQ + q * RS + dd);
            const s8v ak = *(const s8v*)(sK + k * RS + dd);
#pragma unroll
            for (int e = 0; e < 8; ++e)
                s = fmaf(bu2f((ushort)aq[e]), bu2f((ushort)ak[e]), s);
        }
        sS[q][k] = s * scale;
    }
    __syncthreads();

    if (lane < SQ) {   // softmax over k (serial; SK <= 32)
        float* row = sS[lane];
        float mx = row[0];
#pragma unroll
        for (int k = 1; k < SK; ++k) mx = fmaxf(mx, row[k]);
        float sum = 0.f;
#pragma unroll
        for (int k = 0; k < SK; ++k) { const float e = __expf(row[k] - mx); row[k] = e; sum += e; }
        const float inv = 1.f / sum;
#pragma unroll
        for (int k = 0; k < SK; ++k) row[k] *= inv;
    }
    __syncthreads();

    // PV + residual: lane owns head-dim d0 = lane
    float acc[SQ];
#pragma unroll
    for (int q = 0; q < SQ; ++q) acc[q] = 0.f;
#pragma unroll 4
    for (int k = 0; k < SK; ++k) {
        const float v = bu2f(sV[k * RS + lane]);
#pragma unroll
        for (int q = 0; q < SQ; ++q) acc[q] = fmaf(sS[q][k], v, acc[q]);
    }
    const size_t obase = (size_t)b * SQ * D + h * 64 + lane;
#pragma unroll
    for (int q = 0; q < SQ; ++q)
        Ob[obase + (size_t)q * D] = f2bu(bu2f(sQ[q * RS + lane]) + acc[q]);
}

// ---------------- final: row-LN + mean pool over 32 rows -> fp32 out ----------------
__global__ __launch_bounds__(512) void ln_meanpool(
    const ushort* __restrict__ U, const float* __restrict__ gg,
    const float* __restrict__ bb, float* __restrict__ outp)
{
    __shared__ float sP[8][512];
    const int tid = threadIdx.x, lane = tid & 63, wv = tid >> 6;
    const size_t b = blockIdx.x;
    float a[8];
#pragma unroll
    for (int j = 0; j < 8; ++j) a[j] = 0.f;
    for (int i = wv; i < 32; i += 8) {
        const ushort* u = U + ((size_t)b * 32 + i) * D;
        float v[8];
#pragma unroll
        for (int j = 0; j < 8; ++j) v[j] = bu2f(u[lane + 64 * j]);
        float s = 0.f;
#pragma unroll
        for (int j = 0; j < 8; ++j) s += v[j];
        s = wave_sum(s);
        const float mu = s * (1.f / 512.f);
        float q2 = 0.f;
#pragma unroll
        for (int j = 0; j < 8; ++j) { const float t = v[j] - mu; q2 = fmaf(t, t, q2); }
        q2 = wave_sum(q2);
        const float inv = rsqrtf(q2 * (1.f / 512.f) + 1e-5f);
#pragma unroll
        for (int j = 0; j < 8; ++j) {
            const int d0 = lane + 64 * j;
            a[j] += (v[j] - mu) * inv * gg[d0] + bb[d0];
        }
    }
#pragma unroll
    for (int j = 0; j < 8; ++j) sP[wv][lane + 64 * j] = a[j];
    __syncthreads();
    float s = 0.f;
#pragma unroll
    for (int w = 0; w < 8; ++w) s += sP[w][tid];
    outp[b * D + tid] = s * (1.f / 32.f);
}

extern "C" void kernel_launch(void* const* d_in, const int* in_sizes, int n_in,
                              void* d_out, int out_size, void* d_ws, size_t ws_size,
                              hipStream_t stream) {
    (void)in_sizes; (void)n_in; (void)out_size; (void)ws_size;

    const float* x     = (const float*)d_in[0];
    const float* I     = (const float*)d_in[1];
    const float* W0    = (const float*)d_in[2];
    const float* bqkv0 = (const float*)d_in[3];
    const float* Wo0   = (const float*)d_in[4];
    const float* bo0   = (const float*)d_in[5];
    const float* g00   = (const float*)d_in[6];
    const float* b00   = (const float*)d_in[7];
    const float* g01   = (const float*)d_in[8];
    const float* b01   = (const float*)d_in[9];
    const float* W1    = (const float*)d_in[10];
    const float* bqkv1 = (const float*)d_in[11];
    const float* Wo1   = (const float*)d_in[12];
    const float* bo1   = (const float*)d_in[13];
    const float* g10   = (const float*)d_in[14];
    const float* b10   = (const float*)d_in[15];
    const float* g11   = (const float*)d_in[16];
    const float* b11   = (const float*)d_in[17];

    const float* Wq0 = W0;     const float* Wk0 = W0 + D * D;  const float* Wv0 = W0 + 2 * D * D;
    const float* bq0 = bqkv0;  const float* bk0 = bqkv0 + D;   const float* bv0 = bqkv0 + 2 * D;
    const float* Wq1 = W1;     const float* Wk1 = W1 + D * D;  const float* Wv1 = W1 + 2 * D * D;
    const float* bq1 = bqkv1;  const float* bk1 = bqkv1 + D;   const float* bv1 = bqkv1 + 2 * D;

    // ---- workspace: Q0b | Wt(7x512KB) | P0..P3 (64MB each) ≈ 260MB ----
    char* ws = (char*)d_ws;
    ushort* Q0b = (ushort*)ws;
    ushort* Wt  = (ushort*)(ws + 32768);
    char* base = ws + 32768 + 7 * 524288;
    ushort* P0 = (ushort*)(base);
    ushort* P1 = (ushort*)(base + ((size_t)64 << 20));
    ushort* P2 = (ushort*)(base + ((size_t)128 << 20));
    ushort* P3 = (ushort*)(base + ((size_t)192 << 20));
    const size_t HALF = (size_t)16 << 20;   // 32MB in ushorts
    ushort* P0hi = P0 + HALF;
    ushort* P1hi = P1 + HALF;
    ushort* P3hi = P3 + HALF;

    ushort* WtK0 = Wt + 0 * 262144;
    ushort* WtV0 = Wt + 1 * 262144;
    ushort* WtO0 = Wt + 2 * 262144;
    ushort* WtQ1 = Wt + 3 * 262144;
    ushort* WtK1 = Wt + 4 * 262144;
    ushort* WtV1 = Wt + 5 * 262144;
    ushort* WtO1 = Wt + 6 * 262144;

    WPtrs wp; wp.s[0] = Wk0; wp.s[1] = Wv0; wp.s[2] = Wo0; wp.s[3] = Wq1;
    wp.s[4] = Wk1; wp.s[5] = Wv1; wp.s[6] = Wo1;
    wtrans7<<<dim3(16, 16, 7), 256, 0, stream>>>(wp, Wt);
    q0_kernel<<<MIND, 256, 0, stream>>>(I, Wq0, bq0, Q0b);
    conv_bf16<<<4096, 256, 0, stream>>>(x, P0, (long)BATCH * SEQ * D / 4);

    constexpr int GBS = BATCH * SEQ / 64;   // 1024 blocks (M = 65536)
    constexpr int GBM = BATCH * MIND / 64;  // 512 blocks  (M = 32768)
    const dim3 ag(BATCH, 8);

    // ================= ISAB 1 (A = x in P0, no input LN) =================
    gemm512<false, false><<<GBS, 512, 0, stream>>>(P0, WtK0, bk0, g00, b00, P1);     // K0
    gemm512<false, false><<<GBS, 512, 0, stream>>>(P0, WtV0, bv0, g00, b00, P2);     // V0
    attn_core<MIND, SEQ, true><<<ag, 64, 0, stream>>>(Q0b, P1, P2, P3);              // O0 -> P3.lo
    gemm512<true, true><<<GBM, 512, 0, stream>>>(P3, WtO0, bo0, g00, b00, P3hi);     // U0 = ln0+FFN
    gemm512<false, true><<<GBM, 512, 0, stream>>>(P3hi, WtK1, bk1, g01, b01, P1);    // K1 (ln1 in-stage)
    gemm512<false, true><<<GBM, 512, 0, stream>>>(P3hi, WtV1, bv1, g01, b01, P1hi);  // V1
    gemm512<false, false><<<GBS, 512, 0, stream>>>(P0, WtQ1, bq1, g00, b00, P2);     // Q1
    attn_core<SEQ, MIND, false><<<ag, 64, 0, stream>>>(P2, P1, P1hi, P0);            // O1 -> P0
    gemm512<true, true><<<GBS, 512, 0, stream>>>(P0, WtO1, bo1, g10, b10, P3);       // U1 = ln0+FFN

    // ================= ISAB 2 (A = U1 in P3, LN(g11,b11) in-stage) =================
    gemm512<false, true><<<GBS, 512, 0, stream>>>(P3, WtK0, bk0, g11, b11, P1);      // K0
    gemm512<false, true><<<GBS, 512, 0, stream>>>(P3, WtV0, bv0, g11, b11, P2);      // V0
    attn_core<MIND, SEQ, true><<<ag, 64, 0, stream>>>(Q0b, P1, P2, P0);              // O0 -> P0.lo
    gemm512<true, true><<<GBM, 512, 0, stream>>>(P0, WtO0, bo0, g00, b00, P0hi);     // U0
    gemm512<false, true><<<GBM, 512, 0, stream>>>(P0hi, WtK1, bk1, g01, b01, P1);    // K1
    gemm512<false, true><<<GBM, 512, 0, stream>>>(P0hi, WtV1, bv1, g01, b01, P1hi);  // V1
    gemm512<false, true><<<GBS, 512, 0, stream>>>(P3, WtQ1, bq1, g11, b11, P2);      // Q1
    attn_core<SEQ, MIND, false><<<ag, 64, 0, stream>>>(P2, P1, P1hi, P3);            // O1 -> P3
    gemm512<true, true><<<GBS, 512, 0, stream>>>(P3, WtO1, bo1, g10, b10, P0);       // U1 -> P0

    ln_meanpool<<<BATCH, 512, 0, stream>>>(P0, g11, b11, (float*)d_out);
}